// Round 13
// baseline (432.280 us; speedup 1.0000x reference)
//
#include <hip/hip_runtime.h>

// ---------------------------------------------------------------------------
// LSHSampledLayer: logits = x @ W[ids]^T + b[ids]; kth-value thresholds;
// masked-mean cosine-sim triplet loss on random projections.
// N=1024, D=K=1024, C=S=32768, P=128.
// ---------------------------------------------------------------------------

using short8v = __attribute__((ext_vector_type(8))) short;
using f32x4   = __attribute__((ext_vector_type(4))) float;

#define AS1C(p) ((const __attribute__((address_space(1))) void*)(p))
#define AS3(p)  ((__attribute__((address_space(3))) void*)(p))

__device__ __forceinline__ unsigned short f2bf(float f) {
  union { float f; unsigned u; } v; v.f = f;
  unsigned u = v.u;
  return (unsigned short)((u + 0x7FFFu + ((u >> 16) & 1u)) >> 16);  // RNE
}
__device__ __forceinline__ float bf2f(unsigned short s) {
  return __uint_as_float(((unsigned)s) << 16);
}

// ---- K1: gather W[ids]->bf16, b[ids]->f32, cast x->bf16; + qn blocks -------
__global__ __launch_bounds__(256) void k_gather(
    const float* __restrict__ W, const float* __restrict__ bb,
    const float* __restrict__ x, const int* __restrict__ ids,
    unsigned short* __restrict__ swb, float* __restrict__ sbg,
    unsigned short* __restrict__ xb, float* __restrict__ scal,
    const float* __restrict__ rp, unsigned short* __restrict__ qnb) {
  const int t = threadIdx.x;
  if (blockIdx.x >= 2048) {  // ---- qn part: 256 blocks ----
    __shared__ float xs[4][1024];
    __shared__ float part[4][2];
    const int r0 = (blockIdx.x - 2048) * 4;
#pragma unroll
    for (int i = 0; i < 4; ++i) {
      int idx = i * 256 + t, rr = idx >> 8, c4 = idx & 255;
      *(float4*)&xs[rr][c4 * 4] = *(const float4*)&x[(size_t)(r0 + rr) * 1024 + c4 * 4];
    }
    __syncthreads();
    const int col = t & 127, rsel = t >> 7;
    float a0 = 0.f, a1 = 0.f;
    for (int k = 0; k < 1024; k += 4) {
      float4 xa = *(const float4*)&xs[rsel][k];
      float4 xbv = *(const float4*)&xs[rsel + 2][k];
      float av[4] = {xa.x, xa.y, xa.z, xa.w};
      float bv[4] = {xbv.x, xbv.y, xbv.z, xbv.w};
#pragma unroll
      for (int j = 0; j < 4; ++j) {
        float rv = rp[(size_t)(k + j) * 128 + col];
        a0 += av[j] * rv;
        a1 += bv[j] * rv;
      }
    }
    { float rv = rp[(size_t)1024 * 128 + col]; a0 += rv; a1 += rv; }
    float s0 = a0 * a0, s1 = a1 * a1;
#pragma unroll
    for (int m = 1; m < 64; m <<= 1) { s0 += __shfl_xor(s0, m, 64); s1 += __shfl_xor(s1, m, 64); }
    if ((t & 63) == 0) { part[t >> 6][0] = s0; part[t >> 6][1] = s1; }
    __syncthreads();
    float n0 = part[2 * rsel][0] + part[2 * rsel + 1][0];
    float n1 = part[2 * rsel][1] + part[2 * rsel + 1][1];
    qnb[(size_t)(r0 + rsel) * 128 + col]     = f2bf(a0 / fmaxf(sqrtf(n0), 1e-6f));
    qnb[(size_t)(r0 + rsel + 2) * 128 + col] = f2bf(a1 / fmaxf(sqrtf(n1), 1e-6f));
    return;
  }
  if (blockIdx.x == 0 && t < 8) scal[t] = 0.f;  // zero accumulators + counter
  for (int blk = blockIdx.x; blk < 33792; blk += 2048) {
    if (blk < 32768) {
      const int id = ids[blk];
      float4 v = *(const float4*)&W[(size_t)id * 1024 + t * 4];
      ushort4 o; o.x = f2bf(v.x); o.y = f2bf(v.y); o.z = f2bf(v.z); o.w = f2bf(v.w);
      *(ushort4*)&swb[(size_t)blk * 1024 + t * 4] = o;
      if (t == 0) sbg[blk] = bb[id];
    } else {
      const int r = blk - 32768;
      float4 v = *(const float4*)&x[(size_t)r * 1024 + t * 4];
      ushort4 o; o.x = f2bf(v.x); o.y = f2bf(v.y); o.z = f2bf(v.z); o.w = f2bf(v.w);
      *(ushort4*)&xb[(size_t)r * 1024 + t * 4] = o;
    }
  }
}

// ---- swizzled staging: 128x32 bf16 tile, global -> LDS ---------------------
// Row-major linear dest (coalesced); within-row chunk XOR c' = c ^ ((row>>1)&3)
// applied on the SOURCE; reads use the same involution -> 2-way = free.
__device__ __forceinline__ void stage_sw(const unsigned short* g, int lda,
                                         unsigned short* l, int t) {
#pragma unroll
  for (int i = 0; i < 2; ++i) {
    const int idx = i * 256 + t;
    const int row = idx >> 2;
    const int c = (idx & 3) ^ ((row >> 1) & 3);
    const unsigned short* gp = g + (size_t)row * lda + c * 8;
    __builtin_amdgcn_global_load_lds(AS1C(gp), AS3(l + idx * 8), 16, 0, 0);
  }
}

__device__ __forceinline__ void stage_rp(const float* __restrict__ rp, int k0,
                                         unsigned short* l, int t) {
#pragma unroll
  for (int ii = 0; ii < 4; ++ii) {
    int idx = ii * 256 + t;            // 0..1023
    int kk = idx & 31, c4 = idx >> 5;  // kk fast -> conflict-free LDS writes
    float4 v = *(const float4*)&rp[(size_t)(k0 + kk) * 128 + c4 * 4];
    l[(c4 * 4 + 0) * 32 + kk] = f2bf(v.x);
    l[(c4 * 4 + 1) * 32 + kk] = f2bf(v.y);
    l[(c4 * 4 + 2) * 32 + kk] = f2bf(v.z);
    l[(c4 * 4 + 3) * 32 + kk] = f2bf(v.w);
  }
}

// ---- K4: merged GEMM (blocks 0..2047) + wn (blocks 2048..2303) -------------
// GEMM path: R9-proven 128x128, 4x1 waves, swizzled coalesced staging,
// bijective XCD swizzle, 0 bank conflicts (104 us measured).
// wn path: wp = [W[ids],b[ids]] @ rp, row-normalize -> wnb (independent work,
// hides under the GEMM instead of serializing after it).
__global__ __launch_bounds__(256) void k_gemm_wn(
    const unsigned short* __restrict__ A, const unsigned short* __restrict__ B,
    const float* __restrict__ sbg, float* __restrict__ out,
    const float* __restrict__ rp, unsigned short* __restrict__ wnb) {
  __shared__ unsigned short AsU[2][128 * 32];
  __shared__ unsigned short BsU[2][128 * 32];
  __shared__ float nbuf[2][128];
  const int t = threadIdx.x;
  const int l = t & 63, w = t >> 6;
  const int lr = l & 15, lk = l >> 4;
  const int ach = (lk ^ ((lr >> 1) & 3)) * 8;  // swizzled chunk (per-lane const)

  if (blockIdx.x >= 2048) {  // ================= wn path =================
    const int r0 = (blockIdx.x - 2048) * 128;
    const unsigned short* Ag = B + (size_t)r0 * 1024;  // B == swb
    f32x4 acc[4][4];
#pragma unroll
    for (int m = 0; m < 4; ++m)
#pragma unroll
      for (int n = 0; n < 4; ++n) acc[m][n] = f32x4{0.f, 0.f, 0.f, 0.f};
    stage_sw(Ag, 1024, &AsU[0][0], t);
    stage_rp(rp, 0, &BsU[0][0], t);
    const int wm = w >> 1, wn = w & 1;
    const int kch = lk * 8;
    for (int kt = 0; kt < 32; ++kt) {
      const int cur = kt & 1;
      __syncthreads();
      if (kt + 1 < 32) {
        stage_sw(Ag + (kt + 1) * 32, 1024, &AsU[cur ^ 1][0], t);
        stage_rp(rp, (kt + 1) * 32, &BsU[cur ^ 1][0], t);
      }
      short8v a[4], b[4];
#pragma unroll
      for (int m = 0; m < 4; ++m) a[m] = *(const short8v*)&AsU[cur][(wm * 64 + m * 16 + lr) * 32 + ach];
#pragma unroll
      for (int n = 0; n < 4; ++n) b[n] = *(const short8v*)&BsU[cur][(wn * 64 + n * 16 + lr) * 32 + kch];
#pragma unroll
      for (int m = 0; m < 4; ++m)
#pragma unroll
        for (int n = 0; n < 4; ++n)
          acc[m][n] = __builtin_amdgcn_mfma_f32_16x16x32_bf16(a[m], b[n], acc[m][n], 0, 0, 0);
    }
    const float* rpl = rp + (size_t)1024 * 128;
    float sb_r[4][4];
#pragma unroll
    for (int m = 0; m < 4; ++m)
#pragma unroll
      for (int i = 0; i < 4; ++i)
        sb_r[m][i] = sbg[r0 + wm * 64 + m * 16 + lk * 4 + i];
#pragma unroll
    for (int n = 0; n < 4; ++n) {
      const int gc = wn * 64 + n * 16 + lr;
      const float rl = rpl[gc];
#pragma unroll
      for (int m = 0; m < 4; ++m)
#pragma unroll
        for (int i = 0; i < 4; ++i) acc[m][n][i] += sb_r[m][i] * rl;
    }
#pragma unroll
    for (int m = 0; m < 4; ++m)
#pragma unroll
      for (int i = 0; i < 4; ++i) {
        float s = 0.f;
#pragma unroll
        for (int n = 0; n < 4; ++n) s += acc[m][n][i] * acc[m][n][i];
#pragma unroll
        for (int msk = 1; msk < 16; msk <<= 1) s += __shfl_xor(s, msk, 64);
        if (lr == 0) nbuf[wn][wm * 64 + m * 16 + lk * 4 + i] = s;
      }
    __syncthreads();
#pragma unroll
    for (int m = 0; m < 4; ++m)
#pragma unroll
      for (int i = 0; i < 4; ++i) {
        const int lrow = wm * 64 + m * 16 + lk * 4 + i;
        const float n2 = nbuf[0][lrow] + nbuf[1][lrow];
        const float sc = 1.f / fmaxf(sqrtf(n2), 1e-6f);
#pragma unroll
        for (int n = 0; n < 4; ++n) {
          const int gc = wn * 64 + n * 16 + lr;
          wnb[(size_t)(r0 + lrow) * 128 + gc] = f2bf(acc[m][n][i] * sc);
        }
      }
    return;
  }
  // ================= GEMM path (identical to R9) =================
  const int lb = (blockIdx.x & 7) * 256 + (blockIdx.x >> 3);
  const int bm = lb & 7, bn = lb >> 3;
  const unsigned short* Ag = A + (size_t)bm * 128 * 1024;
  const unsigned short* Bg = B + (size_t)bn * 128 * 1024;
  f32x4 acc[2][8];
#pragma unroll
  for (int m = 0; m < 2; ++m)
#pragma unroll
    for (int n = 0; n < 8; ++n) acc[m][n] = f32x4{0.f, 0.f, 0.f, 0.f};
  stage_sw(Ag, 1024, &AsU[0][0], t);
  stage_sw(Bg, 1024, &BsU[0][0], t);
  for (int kt = 0; kt < 32; ++kt) {
    const int cur = kt & 1;
    __syncthreads();
    if (kt + 1 < 32) {
      stage_sw(Ag + (kt + 1) * 32, 1024, &AsU[cur ^ 1][0], t);
      stage_sw(Bg + (kt + 1) * 32, 1024, &BsU[cur ^ 1][0], t);
    }
    short8v a[2], b[8];
#pragma unroll
    for (int m = 0; m < 2; ++m)
      a[m] = *(const short8v*)&AsU[cur][(w * 32 + m * 16 + lr) * 32 + ach];
#pragma unroll
    for (int n = 0; n < 8; ++n)
      b[n] = *(const short8v*)&BsU[cur][(n * 16 + lr) * 32 + ach];
#pragma unroll
    for (int m = 0; m < 2; ++m)
#pragma unroll
      for (int n = 0; n < 8; ++n)
        acc[m][n] = __builtin_amdgcn_mfma_f32_16x16x32_bf16(a[m], b[n], acc[m][n], 0, 0, 0);
  }
  const int rb = bm * 128 + w * 32, cb = bn * 128;
#pragma unroll
  for (int n = 0; n < 8; ++n) {
    const int gc = cb + n * 16 + lr;
    const float bias = sbg[gc];
#pragma unroll
    for (int m = 0; m < 2; ++m)
#pragma unroll
      for (int i = 0; i < 4; ++i) {
        const int gr = rb + m * 16 + lk * 4 + i;
        out[(size_t)gr * 32768 + gc] = acc[m][n][i] + bias;
      }
  }
}

// ---- K5: single-HBM-pass bf16-exact kthvalue (1024 thr -> 32 waves/CU) -----
__global__ __launch_bounds__(1024) void k_hist(
    const float* __restrict__ logits, const float* __restrict__ sbg,
    float* __restrict__ scal) {
  __shared__ unsigned short rowm[32768];  // 64 KiB mapped keys
  __shared__ unsigned hist[2048];
  __shared__ unsigned scanbuf[1024];
  __shared__ unsigned hsub[64];
  __shared__ int res[4];
  const int t = threadIdx.x, row = blockIdx.x;
  for (int i = t; i < 2048; i += 1024) hist[i] = 0u;
  if (t < 64) hsub[t] = 0u;
  __syncthreads();
  const float* lp = logits + (size_t)row * 32768;
  for (int c = t * 4; c < 32768; c += 4096) {
    const float4 lv = *(const float4*)&lp[c];
    const float4 sb4 = *(const float4*)&sbg[c];
    const float pr[4] = {lv.x - sb4.x, lv.y - sb4.y, lv.z - sb4.z, lv.w - sb4.w};
    unsigned short mm[4];
#pragma unroll
    for (int j = 0; j < 4; ++j) {
      const unsigned short bbf = f2bf(pr[j]);
      const unsigned m = (bbf & 0x8000u) ? (0xFFFFu ^ (unsigned)bbf)
                                         : ((unsigned)bbf | 0x8000u);
      mm[j] = (unsigned short)m;
      atomicAdd(&hist[m >> 5], 1u);
    }
    *(ushort4*)&rowm[c] = make_ushort4(mm[0], mm[1], mm[2], mm[3]);
  }
  __syncthreads();
  {  // 2048-bin scan over 1024 threads (2 bins each)
    unsigned s = hist[t * 2] + hist[t * 2 + 1];
    scanbuf[t] = s;
    __syncthreads();
    unsigned x = s;
    for (int off = 1; off < 1024; off <<= 1) {
      unsigned y = (t >= off) ? scanbuf[t - off] : 0u;
      __syncthreads();
      x += y; scanbuf[t] = x;
      __syncthreads();
    }
    unsigned run = x - s;
    const unsigned K1R = 32734u, K2R = 16383u;  // 0-indexed kth ranks
#pragma unroll
    for (int j = 0; j < 2; ++j) {
      unsigned c = hist[t * 2 + j];
      if (K1R >= run && K1R < run + c) { res[0] = t * 2 + j; res[1] = (int)(K1R - run); }
      if (K2R >= run && K2R < run + c) { res[2] = t * 2 + j; res[3] = (int)(K2R - run); }
      run += c;
    }
  }
  __syncthreads();
  const unsigned bin1 = (unsigned)res[0], r1 = (unsigned)res[1];
  const unsigned bin2 = (unsigned)res[2], r2 = (unsigned)res[3];
  for (int c = t; c < 32768; c += 1024) {
    const unsigned m = rowm[c];
    const unsigned bq = m >> 5;
    if (bq == bin1) atomicAdd(&hsub[m & 31], 1u);
    if (bq == bin2) atomicAdd(&hsub[32 + (m & 31)], 1u);
  }
  __syncthreads();
  if (t == 0) {
    unsigned a_ = 0; int sub1 = 31;
    for (int j = 0; j < 32; ++j) { if (r1 < a_ + hsub[j]) { sub1 = j; break; } a_ += hsub[j]; }
    a_ = 0; int sub2 = 31;
    for (int j = 0; j < 32; ++j) { if (r2 < a_ + hsub[32 + j]) { sub2 = j; break; } a_ += hsub[32 + j]; }
    const unsigned m1 = (bin1 << 5) | (unsigned)sub1;
    const unsigned m2 = (bin2 << 5) | (unsigned)sub2;
    const float kv1 = bf2f((unsigned short)((m1 & 0x8000u) ? (m1 & 0x7FFFu) : (0xFFFFu ^ m1)));
    const float kv2 = bf2f((unsigned short)((m2 & 0x8000u) ? (m2 & 0x7FFFu) : (0xFFFFu ^ m2)));
    atomicAdd(&scal[0], kv1);   // kth-value sums; k_sim divides by 1024
    atomicAdd(&scal[1], kv2);
  }
}

// ---- K7: sim = qn @ wn^T fused with masked sums + last-block finalize ------
__global__ __launch_bounds__(256) void k_sim(
    const unsigned short* __restrict__ A, const unsigned short* __restrict__ B,
    const float* __restrict__ logits, const float* __restrict__ sbg,
    float* __restrict__ scal, float* __restrict__ out) {
  __shared__ unsigned short smem[128 * 128];  // 32 KiB: As/Bs then simb
  __shared__ float red[4][4];
  unsigned short* As = smem;                 //  8 KiB
  unsigned short* Bs = smem + 128 * 32;      //  8 KiB
  unsigned short* simb = smem;               // 32 KiB (after MFMA loop)
  const int t = threadIdx.x;
  const int bm = blockIdx.x & 7, bn = blockIdx.x >> 3;
  const unsigned short* Ag = A + (size_t)bm * 128 * 128;
  const unsigned short* Bg = B + (size_t)bn * 128 * 128;
  f32x4 acc[4][4];
#pragma unroll
  for (int m = 0; m < 4; ++m)
#pragma unroll
    for (int n = 0; n < 4; ++n) acc[m][n] = f32x4{0.f, 0.f, 0.f, 0.f};
  const int l = t & 63, w = t >> 6, wm = w >> 1, wn = w & 1;
  const int lr = l & 15, lk = l >> 4;
  const int ach = (lk ^ ((lr >> 1) & 3)) * 8;
  for (int kt = 0; kt < 4; ++kt) {
    stage_sw(Ag + kt * 32, 128, As, t);
    stage_sw(Bg + kt * 32, 128, Bs, t);
    __syncthreads();
    short8v a[4], b[4];
#pragma unroll
    for (int m = 0; m < 4; ++m) a[m] = *(const short8v*)&As[(wm * 64 + m * 16 + lr) * 32 + ach];
#pragma unroll
    for (int n = 0; n < 4; ++n) b[n] = *(const short8v*)&Bs[(wn * 64 + n * 16 + lr) * 32 + ach];
#pragma unroll
    for (int m = 0; m < 4; ++m)
#pragma unroll
      for (int n = 0; n < 4; ++n)
        acc[m][n] = __builtin_amdgcn_mfma_f32_16x16x32_bf16(a[m], b[n], acc[m][n], 0, 0, 0);
    __syncthreads();
  }
#pragma unroll
  for (int m = 0; m < 4; ++m)
#pragma unroll
    for (int n = 0; n < 4; ++n) {
      const int col = wn * 64 + n * 16 + lr;
#pragma unroll
      for (int i = 0; i < 4; ++i) {
        const int row = wm * 64 + m * 16 + lk * 4 + i;
        simb[row * 128 + col] = f2bf(acc[m][n][i]);
      }
    }
  __syncthreads();
  const float t1 = fmaxf(scal[0] * (1.f / 1024.f), 0.f);
  const float t2 = scal[1] * (1.f / 1024.f);
  const int rb0 = bm * 128, cb0 = bn * 128;
  float ps = 0.f, pc = 0.f, ns = 0.f, nc = 0.f;
#pragma unroll
  for (int it = 0; it < 16; ++it) {
    const int idx = it * 256 + t;
    const int rr = idx >> 5;
    const int c4 = idx & 31;
    const float4 lv = *(const float4*)&logits[(size_t)(rb0 + rr) * 32768 + cb0 + c4 * 4];
    const float4 sb4 = *(const float4*)&sbg[cb0 + c4 * 4];
    const ushort4 sv = *(const ushort4*)&simb[rr * 128 + c4 * 4];
    const float pr[4] = {lv.x - sb4.x, lv.y - sb4.y, lv.z - sb4.z, lv.w - sb4.w};
    const float sm[4] = {bf2f(sv.x), bf2f(sv.y), bf2f(sv.z), bf2f(sv.w)};
#pragma unroll
    for (int j = 0; j < 4; ++j) {
      if (pr[j] > t1) { ps += sm[j]; pc += 1.f; }
      if (pr[j] < t2) { ns += sm[j]; nc += 1.f; }
    }
  }
#pragma unroll
  for (int m = 1; m < 64; m <<= 1) {
    ps += __shfl_xor(ps, m, 64); pc += __shfl_xor(pc, m, 64);
    ns += __shfl_xor(ns, m, 64); nc += __shfl_xor(nc, m, 64);
  }
  if (l == 0) { red[w][0] = ps; red[w][1] = pc; red[w][2] = ns; red[w][3] = nc; }
  __syncthreads();
  if (t == 0) {
    atomicAdd(&scal[2], red[0][0] + red[1][0] + red[2][0] + red[3][0]);
    atomicAdd(&scal[3], red[0][1] + red[1][1] + red[2][1] + red[3][1]);
    atomicAdd(&scal[4], red[0][2] + red[1][2] + red[2][2] + red[3][2]);
    atomicAdd(&scal[5], red[0][3] + red[1][3] + red[2][3] + red[3][3]);
    __threadfence();
    unsigned* cnt = (unsigned*)&scal[6];
    const unsigned old = atomicAdd(cnt, 1u);
    if (old == 2047u) {  // last block: all sums are globally visible
      __threadfence();
      const float tps = atomicAdd(&scal[2], 0.f);
      const float tpc = atomicAdd(&scal[3], 0.f);
      const float tns = atomicAdd(&scal[4], 0.f);
      const float tnc = atomicAdd(&scal[5], 0.f);
      const float sp = tps / fmaxf(tpc, 1.f);
      const float sn = tns / fmaxf(tnc, 1.f);
      out[33554432] = fmaxf(sn - sp + 1.f, 0.f);
    }
  }
}

// ---------------------------------------------------------------------------
extern "C" void kernel_launch(void* const* d_in, const int* in_sizes, int n_in,
                              void* d_out, int out_size, void* d_ws, size_t ws_size,
                              hipStream_t stream) {
  const float* x  = (const float*)d_in[0];
  const float* W  = (const float*)d_in[1];
  const float* b  = (const float*)d_in[2];
  const float* rp = (const float*)d_in[3];
  const int*  ids = (const int*)d_in[4];
  float* out = (float*)d_out;
  char* ws = (char*)d_ws;

  unsigned short* swb = (unsigned short*)(ws);                 // 64 MiB
  unsigned short* xb  = (unsigned short*)(ws + 67108864);      //  2 MiB
  float*          sbg = (float*)(ws + 69206016);               // 128 KiB
  unsigned short* qnb = (unsigned short*)(ws + 69337088);      // 256 KiB
  unsigned short* wnb = (unsigned short*)(ws + 69599232);      //  8 MiB
  float*         scal = (float*)(ws + 78012416);               // 8 floats

  k_gather <<<2304,  256, 0, stream>>>(W, b, x, ids, swb, sbg, xb, scal, rp, qnb);
  k_gemm_wn<<<2304,  256, 0, stream>>>(xb, swb, sbg, out, rp, wnb);
  k_hist   <<<1024, 1024, 0, stream>>>(out, sbg, scal);
  k_sim    <<<2048,  256, 0, stream>>>(qnb, wnb, out, sbg, scal, out);
}

// Round 14
// 412.742 us; speedup vs baseline: 1.0473x; 1.0473x over previous
//
#include <hip/hip_runtime.h>

// ---------------------------------------------------------------------------
// LSHSampledLayer: logits = x @ W[ids]^T + b[ids]; kth-value thresholds;
// masked-mean cosine-sim triplet loss on random projections.
// N=1024, D=K=1024, C=S=32768, P=128.
// ---------------------------------------------------------------------------

using short8v = __attribute__((ext_vector_type(8))) short;
using f32x4   = __attribute__((ext_vector_type(4))) float;

#define AS1C(p) ((const __attribute__((address_space(1))) void*)(p))
#define AS3(p)  ((__attribute__((address_space(3))) void*)(p))

__device__ __forceinline__ unsigned short f2bf(float f) {
  union { float f; unsigned u; } v; v.f = f;
  unsigned u = v.u;
  return (unsigned short)((u + 0x7FFFu + ((u >> 16) & 1u)) >> 16);  // RNE
}
__device__ __forceinline__ float bf2f(unsigned short s) {
  return __uint_as_float(((unsigned)s) << 16);
}

// ---- K1: gather W[ids]->bf16, b[ids]->f32, cast x->bf16; + qn blocks -------
__global__ __launch_bounds__(256) void k_gather(
    const float* __restrict__ W, const float* __restrict__ bb,
    const float* __restrict__ x, const int* __restrict__ ids,
    unsigned short* __restrict__ swb, float* __restrict__ sbg,
    unsigned short* __restrict__ xb, float* __restrict__ scal,
    const float* __restrict__ rp, unsigned short* __restrict__ qnb) {
  const int t = threadIdx.x;
  if (blockIdx.x >= 2048) {  // ---- qn part: 256 blocks ----
    __shared__ float xs[4][1024];
    __shared__ float part[4][2];
    const int r0 = (blockIdx.x - 2048) * 4;
#pragma unroll
    for (int i = 0; i < 4; ++i) {
      int idx = i * 256 + t, rr = idx >> 8, c4 = idx & 255;
      *(float4*)&xs[rr][c4 * 4] = *(const float4*)&x[(size_t)(r0 + rr) * 1024 + c4 * 4];
    }
    __syncthreads();
    const int col = t & 127, rsel = t >> 7;
    float a0 = 0.f, a1 = 0.f;
    for (int k = 0; k < 1024; k += 4) {
      float4 xa = *(const float4*)&xs[rsel][k];
      float4 xbv = *(const float4*)&xs[rsel + 2][k];
      float av[4] = {xa.x, xa.y, xa.z, xa.w};
      float bv[4] = {xbv.x, xbv.y, xbv.z, xbv.w};
#pragma unroll
      for (int j = 0; j < 4; ++j) {
        float rv = rp[(size_t)(k + j) * 128 + col];
        a0 += av[j] * rv;
        a1 += bv[j] * rv;
      }
    }
    { float rv = rp[(size_t)1024 * 128 + col]; a0 += rv; a1 += rv; }
    float s0 = a0 * a0, s1 = a1 * a1;
#pragma unroll
    for (int m = 1; m < 64; m <<= 1) { s0 += __shfl_xor(s0, m, 64); s1 += __shfl_xor(s1, m, 64); }
    if ((t & 63) == 0) { part[t >> 6][0] = s0; part[t >> 6][1] = s1; }
    __syncthreads();
    float n0 = part[2 * rsel][0] + part[2 * rsel + 1][0];
    float n1 = part[2 * rsel][1] + part[2 * rsel + 1][1];
    qnb[(size_t)(r0 + rsel) * 128 + col]     = f2bf(a0 / fmaxf(sqrtf(n0), 1e-6f));
    qnb[(size_t)(r0 + rsel + 2) * 128 + col] = f2bf(a1 / fmaxf(sqrtf(n1), 1e-6f));
    return;
  }
  if (blockIdx.x == 0 && t < 8) scal[t] = 0.f;  // zero accumulators + counter
  for (int blk = blockIdx.x; blk < 33792; blk += 2048) {
    if (blk < 32768) {
      const int id = ids[blk];
      float4 v = *(const float4*)&W[(size_t)id * 1024 + t * 4];
      ushort4 o; o.x = f2bf(v.x); o.y = f2bf(v.y); o.z = f2bf(v.z); o.w = f2bf(v.w);
      *(ushort4*)&swb[(size_t)blk * 1024 + t * 4] = o;
      if (t == 0) sbg[blk] = bb[id];
    } else {
      const int r = blk - 32768;
      float4 v = *(const float4*)&x[(size_t)r * 1024 + t * 4];
      ushort4 o; o.x = f2bf(v.x); o.y = f2bf(v.y); o.z = f2bf(v.z); o.w = f2bf(v.w);
      *(ushort4*)&xb[(size_t)r * 1024 + t * 4] = o;
    }
  }
}

// ---- swizzled staging: 128x32 bf16 tile, global -> LDS ---------------------
// Row-major linear dest (coalesced); within-row chunk XOR c' = c ^ ((row>>1)&3)
// applied on the SOURCE; reads use the same involution -> 2-way = free.
__device__ __forceinline__ void stage_sw(const unsigned short* g, int lda,
                                         unsigned short* l, int t) {
#pragma unroll
  for (int i = 0; i < 2; ++i) {
    const int idx = i * 256 + t;
    const int row = idx >> 2;
    const int c = (idx & 3) ^ ((row >> 1) & 3);
    const unsigned short* gp = g + (size_t)row * lda + c * 8;
    __builtin_amdgcn_global_load_lds(AS1C(gp), AS3(l + idx * 8), 16, 0, 0);
  }
}

__device__ __forceinline__ void stage_rp(const float* __restrict__ rp, int k0,
                                         unsigned short* l, int t) {
#pragma unroll
  for (int ii = 0; ii < 4; ++ii) {
    int idx = ii * 256 + t;            // 0..1023
    int kk = idx & 31, c4 = idx >> 5;  // kk fast -> conflict-free LDS writes
    float4 v = *(const float4*)&rp[(size_t)(k0 + kk) * 128 + c4 * 4];
    l[(c4 * 4 + 0) * 32 + kk] = f2bf(v.x);
    l[(c4 * 4 + 1) * 32 + kk] = f2bf(v.y);
    l[(c4 * 4 + 2) * 32 + kk] = f2bf(v.z);
    l[(c4 * 4 + 3) * 32 + kk] = f2bf(v.w);
  }
}

// ---- K3: wp = [W[ids],b[ids]] @ rp ; wn = normalize rows ; bf16 ------------
__global__ __launch_bounds__(256) void k_wn(
    const unsigned short* __restrict__ swb, const float* __restrict__ rp,
    const float* __restrict__ sbg, unsigned short* __restrict__ wnb) {
  __shared__ unsigned short As[2][128 * 32];
  __shared__ unsigned short Bs[2][128 * 32];
  __shared__ float nbuf[2][128];
  const int t = threadIdx.x;
  const int r0 = blockIdx.x * 128;
  const unsigned short* Ag = swb + (size_t)r0 * 1024;
  f32x4 acc[4][4];
#pragma unroll
  for (int m = 0; m < 4; ++m)
#pragma unroll
    for (int n = 0; n < 4; ++n) acc[m][n] = f32x4{0.f, 0.f, 0.f, 0.f};
  stage_sw(Ag, 1024, &As[0][0], t);
  stage_rp(rp, 0, &Bs[0][0], t);
  const int l = t & 63, w = t >> 6, wm = w >> 1, wn = w & 1;
  const int lr = l & 15, lk = l >> 4;
  const int kch = lk * 8;
  const int ach = (lk ^ ((lr >> 1) & 3)) * 8;  // swizzled chunk for A reads
  for (int kt = 0; kt < 32; ++kt) {
    const int cur = kt & 1;
    __syncthreads();
    if (kt + 1 < 32) {
      stage_sw(Ag + (kt + 1) * 32, 1024, &As[cur ^ 1][0], t);
      stage_rp(rp, (kt + 1) * 32, &Bs[cur ^ 1][0], t);
    }
    short8v a[4], b[4];
#pragma unroll
    for (int m = 0; m < 4; ++m) a[m] = *(const short8v*)&As[cur][(wm * 64 + m * 16 + lr) * 32 + ach];
#pragma unroll
    for (int n = 0; n < 4; ++n) b[n] = *(const short8v*)&Bs[cur][(wn * 64 + n * 16 + lr) * 32 + kch];
#pragma unroll
    for (int m = 0; m < 4; ++m)
#pragma unroll
      for (int n = 0; n < 4; ++n)
        acc[m][n] = __builtin_amdgcn_mfma_f32_16x16x32_bf16(a[m], b[n], acc[m][n], 0, 0, 0);
  }
  const float* rpl = rp + (size_t)1024 * 128;
  float sb_r[4][4];
#pragma unroll
  for (int m = 0; m < 4; ++m)
#pragma unroll
    for (int i = 0; i < 4; ++i)
      sb_r[m][i] = sbg[r0 + wm * 64 + m * 16 + lk * 4 + i];
#pragma unroll
  for (int n = 0; n < 4; ++n) {
    const int gc = wn * 64 + n * 16 + lr;
    const float rl = rpl[gc];
#pragma unroll
    for (int m = 0; m < 4; ++m)
#pragma unroll
      for (int i = 0; i < 4; ++i) acc[m][n][i] += sb_r[m][i] * rl;
  }
#pragma unroll
  for (int m = 0; m < 4; ++m)
#pragma unroll
    for (int i = 0; i < 4; ++i) {
      float s = 0.f;
#pragma unroll
      for (int n = 0; n < 4; ++n) s += acc[m][n][i] * acc[m][n][i];
#pragma unroll
      for (int msk = 1; msk < 16; msk <<= 1) s += __shfl_xor(s, msk, 64);
      if (lr == 0) nbuf[wn][wm * 64 + m * 16 + lk * 4 + i] = s;
    }
  __syncthreads();
#pragma unroll
  for (int m = 0; m < 4; ++m)
#pragma unroll
    for (int i = 0; i < 4; ++i) {
      const int lrow = wm * 64 + m * 16 + lk * 4 + i;
      const float n2 = nbuf[0][lrow] + nbuf[1][lrow];
      const float sc = 1.f / fmaxf(sqrtf(n2), 1e-6f);
#pragma unroll
      for (int n = 0; n < 4; ++n) {
        const int gc = wn * 64 + n * 16 + lr;
        wnb[(size_t)(r0 + lrow) * 128 + gc] = f2bf(acc[m][n][i] * sc);
      }
    }
}

// ---- K4: main GEMM  logits = xb @ swb^T + sb  (128x128, R9-proven) ---------
__global__ __launch_bounds__(256) void k_gemm_main(
    const unsigned short* __restrict__ A, const unsigned short* __restrict__ B,
    const float* __restrict__ sbg, float* __restrict__ out) {
  __shared__ unsigned short As[2][128 * 32];
  __shared__ unsigned short Bs[2][128 * 32];
  const int t = threadIdx.x;
  // 2048 blocks, 8 XCDs, 256 logical tiles per XCD (nwg%8==0 -> bijective)
  const int lb = (blockIdx.x & 7) * 256 + (blockIdx.x >> 3);
  const int bm = lb & 7, bn = lb >> 3;
  const unsigned short* Ag = A + (size_t)bm * 128 * 1024;
  const unsigned short* Bg = B + (size_t)bn * 128 * 1024;
  f32x4 acc[2][8];
#pragma unroll
  for (int m = 0; m < 2; ++m)
#pragma unroll
    for (int n = 0; n < 8; ++n) acc[m][n] = f32x4{0.f, 0.f, 0.f, 0.f};
  stage_sw(Ag, 1024, &As[0][0], t);
  stage_sw(Bg, 1024, &Bs[0][0], t);
  const int l = t & 63, w = t >> 6;        // wave w owns rows w*32..w*32+31
  const int lr = l & 15, lk = l >> 4;
  const int ach = (lk ^ ((lr >> 1) & 3)) * 8;  // swizzled chunk (per-lane const)
  for (int kt = 0; kt < 32; ++kt) {
    const int cur = kt & 1;
    __syncthreads();
    if (kt + 1 < 32) {
      stage_sw(Ag + (kt + 1) * 32, 1024, &As[cur ^ 1][0], t);
      stage_sw(Bg + (kt + 1) * 32, 1024, &Bs[cur ^ 1][0], t);
    }
    short8v a[2], b[8];
#pragma unroll
    for (int m = 0; m < 2; ++m)
      a[m] = *(const short8v*)&As[cur][(w * 32 + m * 16 + lr) * 32 + ach];
#pragma unroll
    for (int n = 0; n < 8; ++n)
      b[n] = *(const short8v*)&Bs[cur][(n * 16 + lr) * 32 + ach];
#pragma unroll
    for (int m = 0; m < 2; ++m)
#pragma unroll
      for (int n = 0; n < 8; ++n)
        acc[m][n] = __builtin_amdgcn_mfma_f32_16x16x32_bf16(a[m], b[n], acc[m][n], 0, 0, 0);
  }
  const int rb = bm * 128 + w * 32, cb = bn * 128;
#pragma unroll
  for (int n = 0; n < 8; ++n) {
    const int gc = cb + n * 16 + lr;
    const float bias = sbg[gc];
#pragma unroll
    for (int m = 0; m < 2; ++m)
#pragma unroll
      for (int i = 0; i < 4; ++i) {
        const int gr = rb + m * 16 + lk * 4 + i;
        out[(size_t)gr * 32768 + gc] = acc[m][n][i] + bias;
      }
  }
}

// ---- K5: single-HBM-pass bf16-exact kthvalue (1024 thr -> 32 waves/CU) -----
__global__ __launch_bounds__(1024) void k_hist(
    const float* __restrict__ logits, const float* __restrict__ sbg,
    float* __restrict__ scal) {
  __shared__ unsigned short rowm[32768];  // 64 KiB mapped keys
  __shared__ unsigned hist[2048];
  __shared__ unsigned scanbuf[1024];
  __shared__ unsigned hsub[64];
  __shared__ int res[4];
  const int t = threadIdx.x, row = blockIdx.x;
  for (int i = t; i < 2048; i += 1024) hist[i] = 0u;
  if (t < 64) hsub[t] = 0u;
  __syncthreads();
  const float* lp = logits + (size_t)row * 32768;
  for (int c = t * 4; c < 32768; c += 4096) {
    const float4 lv = *(const float4*)&lp[c];
    const float4 sb4 = *(const float4*)&sbg[c];
    const float pr[4] = {lv.x - sb4.x, lv.y - sb4.y, lv.z - sb4.z, lv.w - sb4.w};
    unsigned short mm[4];
#pragma unroll
    for (int j = 0; j < 4; ++j) {
      const unsigned short bbf = f2bf(pr[j]);
      const unsigned m = (bbf & 0x8000u) ? (0xFFFFu ^ (unsigned)bbf)
                                         : ((unsigned)bbf | 0x8000u);
      mm[j] = (unsigned short)m;
      atomicAdd(&hist[m >> 5], 1u);
    }
    *(ushort4*)&rowm[c] = make_ushort4(mm[0], mm[1], mm[2], mm[3]);
  }
  __syncthreads();
  {  // 2048-bin scan over 1024 threads (2 bins each)
    unsigned s = hist[t * 2] + hist[t * 2 + 1];
    scanbuf[t] = s;
    __syncthreads();
    unsigned x = s;
    for (int off = 1; off < 1024; off <<= 1) {
      unsigned y = (t >= off) ? scanbuf[t - off] : 0u;
      __syncthreads();
      x += y; scanbuf[t] = x;
      __syncthreads();
    }
    unsigned run = x - s;
    const unsigned K1R = 32734u, K2R = 16383u;  // 0-indexed kth ranks
#pragma unroll
    for (int j = 0; j < 2; ++j) {
      unsigned c = hist[t * 2 + j];
      if (K1R >= run && K1R < run + c) { res[0] = t * 2 + j; res[1] = (int)(K1R - run); }
      if (K2R >= run && K2R < run + c) { res[2] = t * 2 + j; res[3] = (int)(K2R - run); }
      run += c;
    }
  }
  __syncthreads();
  const unsigned bin1 = (unsigned)res[0], r1 = (unsigned)res[1];
  const unsigned bin2 = (unsigned)res[2], r2 = (unsigned)res[3];
  for (int c = t; c < 32768; c += 1024) {
    const unsigned m = rowm[c];
    const unsigned bq = m >> 5;
    if (bq == bin1) atomicAdd(&hsub[m & 31], 1u);
    if (bq == bin2) atomicAdd(&hsub[32 + (m & 31)], 1u);
  }
  __syncthreads();
  if (t == 0) {
    unsigned a_ = 0; int sub1 = 31;
    for (int j = 0; j < 32; ++j) { if (r1 < a_ + hsub[j]) { sub1 = j; break; } a_ += hsub[j]; }
    a_ = 0; int sub2 = 31;
    for (int j = 0; j < 32; ++j) { if (r2 < a_ + hsub[32 + j]) { sub2 = j; break; } a_ += hsub[32 + j]; }
    const unsigned m1 = (bin1 << 5) | (unsigned)sub1;
    const unsigned m2 = (bin2 << 5) | (unsigned)sub2;
    const float kv1 = bf2f((unsigned short)((m1 & 0x8000u) ? (m1 & 0x7FFFu) : (0xFFFFu ^ m1)));
    const float kv2 = bf2f((unsigned short)((m2 & 0x8000u) ? (m2 & 0x7FFFu) : (0xFFFFu ^ m2)));
    atomicAdd(&scal[0], kv1);   // kth-value sums; k_sim divides by 1024
    atomicAdd(&scal[1], kv2);
  }
}

// ---- K7: sim = qn @ wn^T fused with masked sums + last-block finalize ------
__global__ __launch_bounds__(256) void k_sim(
    const unsigned short* __restrict__ A, const unsigned short* __restrict__ B,
    const float* __restrict__ logits, const float* __restrict__ sbg,
    float* __restrict__ scal, float* __restrict__ out) {
  __shared__ unsigned short smem[128 * 128];  // 32 KiB: As/Bs then simb
  __shared__ float red[4][4];
  unsigned short* As = smem;                 //  8 KiB
  unsigned short* Bs = smem + 128 * 32;      //  8 KiB
  unsigned short* simb = smem;               // 32 KiB (after MFMA loop)
  const int t = threadIdx.x;
  const int bm = blockIdx.x & 7, bn = blockIdx.x >> 3;
  const unsigned short* Ag = A + (size_t)bm * 128 * 128;
  const unsigned short* Bg = B + (size_t)bn * 128 * 128;
  f32x4 acc[4][4];
#pragma unroll
  for (int m = 0; m < 4; ++m)
#pragma unroll
    for (int n = 0; n < 4; ++n) acc[m][n] = f32x4{0.f, 0.f, 0.f, 0.f};
  const int l = t & 63, w = t >> 6, wm = w >> 1, wn = w & 1;
  const int lr = l & 15, lk = l >> 4;
  const int ach = (lk ^ ((lr >> 1) & 3)) * 8;
  for (int kt = 0; kt < 4; ++kt) {
    stage_sw(Ag + kt * 32, 128, As, t);
    stage_sw(Bg + kt * 32, 128, Bs, t);
    __syncthreads();
    short8v a[4], b[4];
#pragma unroll
    for (int m = 0; m < 4; ++m) a[m] = *(const short8v*)&As[(wm * 64 + m * 16 + lr) * 32 + ach];
#pragma unroll
    for (int n = 0; n < 4; ++n) b[n] = *(const short8v*)&Bs[(wn * 64 + n * 16 + lr) * 32 + ach];
#pragma unroll
    for (int m = 0; m < 4; ++m)
#pragma unroll
      for (int n = 0; n < 4; ++n)
        acc[m][n] = __builtin_amdgcn_mfma_f32_16x16x32_bf16(a[m], b[n], acc[m][n], 0, 0, 0);
    __syncthreads();
  }
#pragma unroll
  for (int m = 0; m < 4; ++m)
#pragma unroll
    for (int n = 0; n < 4; ++n) {
      const int col = wn * 64 + n * 16 + lr;
#pragma unroll
      for (int i = 0; i < 4; ++i) {
        const int row = wm * 64 + m * 16 + lk * 4 + i;
        simb[row * 128 + col] = f2bf(acc[m][n][i]);
      }
    }
  __syncthreads();
  const float t1 = fmaxf(scal[0] * (1.f / 1024.f), 0.f);
  const float t2 = scal[1] * (1.f / 1024.f);
  const int rb0 = bm * 128, cb0 = bn * 128;
  float ps = 0.f, pc = 0.f, ns = 0.f, nc = 0.f;
#pragma unroll
  for (int it = 0; it < 16; ++it) {
    const int idx = it * 256 + t;
    const int rr = idx >> 5;
    const int c4 = idx & 31;
    const float4 lv = *(const float4*)&logits[(size_t)(rb0 + rr) * 32768 + cb0 + c4 * 4];
    const float4 sb4 = *(const float4*)&sbg[cb0 + c4 * 4];
    const ushort4 sv = *(const ushort4*)&simb[rr * 128 + c4 * 4];
    const float pr[4] = {lv.x - sb4.x, lv.y - sb4.y, lv.z - sb4.z, lv.w - sb4.w};
    const float sm[4] = {bf2f(sv.x), bf2f(sv.y), bf2f(sv.z), bf2f(sv.w)};
#pragma unroll
    for (int j = 0; j < 4; ++j) {
      if (pr[j] > t1) { ps += sm[j]; pc += 1.f; }
      if (pr[j] < t2) { ns += sm[j]; nc += 1.f; }
    }
  }
#pragma unroll
  for (int m = 1; m < 64; m <<= 1) {
    ps += __shfl_xor(ps, m, 64); pc += __shfl_xor(pc, m, 64);
    ns += __shfl_xor(ns, m, 64); nc += __shfl_xor(nc, m, 64);
  }
  if (l == 0) { red[w][0] = ps; red[w][1] = pc; red[w][2] = ns; red[w][3] = nc; }
  __syncthreads();
  if (t == 0) {
    atomicAdd(&scal[2], red[0][0] + red[1][0] + red[2][0] + red[3][0]);
    atomicAdd(&scal[3], red[0][1] + red[1][1] + red[2][1] + red[3][1]);
    atomicAdd(&scal[4], red[0][2] + red[1][2] + red[2][2] + red[3][2]);
    atomicAdd(&scal[5], red[0][3] + red[1][3] + red[2][3] + red[3][3]);
    __threadfence();
    unsigned* cnt = (unsigned*)&scal[6];
    const unsigned old = atomicAdd(cnt, 1u);
    if (old == 2047u) {  // last block: all sums globally visible
      __threadfence();
      const float tps = atomicAdd(&scal[2], 0.f);
      const float tpc = atomicAdd(&scal[3], 0.f);
      const float tns = atomicAdd(&scal[4], 0.f);
      const float tnc = atomicAdd(&scal[5], 0.f);
      const float sp = tps / fmaxf(tpc, 1.f);
      const float sn = tns / fmaxf(tnc, 1.f);
      out[33554432] = fmaxf(sn - sp + 1.f, 0.f);
    }
  }
}

// ---------------------------------------------------------------------------
extern "C" void kernel_launch(void* const* d_in, const int* in_sizes, int n_in,
                              void* d_out, int out_size, void* d_ws, size_t ws_size,
                              hipStream_t stream) {
  const float* x  = (const float*)d_in[0];
  const float* W  = (const float*)d_in[1];
  const float* b  = (const float*)d_in[2];
  const float* rp = (const float*)d_in[3];
  const int*  ids = (const int*)d_in[4];
  float* out = (float*)d_out;
  char* ws = (char*)d_ws;

  unsigned short* swb = (unsigned short*)(ws);                 // 64 MiB
  unsigned short* xb  = (unsigned short*)(ws + 67108864);      //  2 MiB
  float*          sbg = (float*)(ws + 69206016);               // 128 KiB
  unsigned short* qnb = (unsigned short*)(ws + 69337088);      // 256 KiB
  unsigned short* wnb = (unsigned short*)(ws + 69599232);      //  8 MiB
  float*         scal = (float*)(ws + 78012416);               // 8 floats

  k_gather   <<<2304,  256, 0, stream>>>(W, b, x, ids, swb, sbg, xb, scal, rp, qnb);
  k_wn       <<<256,   256, 0, stream>>>(swb, rp, sbg, wnb);
  k_gemm_main<<<2048,  256, 0, stream>>>(xb, swb, sbg, out);
  k_hist     <<<1024, 1024, 0, stream>>>(out, sbg, scal);
  k_sim      <<<2048,  256, 0, stream>>>(qnb, wnb, out, sbg, scal, out);
}

// Round 15
// 322.956 us; speedup vs baseline: 1.3385x; 1.2780x over previous
//
#include <hip/hip_runtime.h>

// ---------------------------------------------------------------------------
// LSHSampledLayer: logits = x @ W[ids]^T + b[ids]; kth-value thresholds;
// masked-mean cosine-sim triplet loss on random projections.
// N=1024, D=K=1024, C=S=32768, P=128.
// ---------------------------------------------------------------------------

using short8v = __attribute__((ext_vector_type(8))) short;
using f32x4   = __attribute__((ext_vector_type(4))) float;

#define AS1C(p) ((const __attribute__((address_space(1))) void*)(p))
#define AS3(p)  ((__attribute__((address_space(3))) void*)(p))

__device__ __forceinline__ unsigned short f2bf(float f) {
  union { float f; unsigned u; } v; v.f = f;
  unsigned u = v.u;
  return (unsigned short)((u + 0x7FFFu + ((u >> 16) & 1u)) >> 16);  // RNE
}
__device__ __forceinline__ float bf2f(unsigned short s) {
  return __uint_as_float(((unsigned)s) << 16);
}

// ---- K1: gather W[ids]->bf16, b[ids]->f32, cast x->bf16; + qn blocks -------
__global__ __launch_bounds__(256) void k_gather(
    const float* __restrict__ W, const float* __restrict__ bb,
    const float* __restrict__ x, const int* __restrict__ ids,
    unsigned short* __restrict__ swb, float* __restrict__ sbg,
    unsigned short* __restrict__ xb, float* __restrict__ scal,
    const float* __restrict__ rp, unsigned short* __restrict__ qnb) {
  const int t = threadIdx.x;
  if (blockIdx.x >= 2048) {  // ---- qn part: 256 blocks ----
    __shared__ float xs[4][1024];
    __shared__ float part[4][2];
    const int r0 = (blockIdx.x - 2048) * 4;
#pragma unroll
    for (int i = 0; i < 4; ++i) {
      int idx = i * 256 + t, rr = idx >> 8, c4 = idx & 255;
      *(float4*)&xs[rr][c4 * 4] = *(const float4*)&x[(size_t)(r0 + rr) * 1024 + c4 * 4];
    }
    __syncthreads();
    const int col = t & 127, rsel = t >> 7;
    float a0 = 0.f, a1 = 0.f;
    for (int k = 0; k < 1024; k += 4) {
      float4 xa = *(const float4*)&xs[rsel][k];
      float4 xbv = *(const float4*)&xs[rsel + 2][k];
      float av[4] = {xa.x, xa.y, xa.z, xa.w};
      float bv[4] = {xbv.x, xbv.y, xbv.z, xbv.w};
#pragma unroll
      for (int j = 0; j < 4; ++j) {
        float rv = rp[(size_t)(k + j) * 128 + col];
        a0 += av[j] * rv;
        a1 += bv[j] * rv;
      }
    }
    { float rv = rp[(size_t)1024 * 128 + col]; a0 += rv; a1 += rv; }
    float s0 = a0 * a0, s1 = a1 * a1;
#pragma unroll
    for (int m = 1; m < 64; m <<= 1) { s0 += __shfl_xor(s0, m, 64); s1 += __shfl_xor(s1, m, 64); }
    if ((t & 63) == 0) { part[t >> 6][0] = s0; part[t >> 6][1] = s1; }
    __syncthreads();
    float n0 = part[2 * rsel][0] + part[2 * rsel + 1][0];
    float n1 = part[2 * rsel][1] + part[2 * rsel + 1][1];
    qnb[(size_t)(r0 + rsel) * 128 + col]     = f2bf(a0 / fmaxf(sqrtf(n0), 1e-6f));
    qnb[(size_t)(r0 + rsel + 2) * 128 + col] = f2bf(a1 / fmaxf(sqrtf(n1), 1e-6f));
    return;
  }
  if (blockIdx.x == 0 && t < 8) scal[t] = 0.f;  // zero accumulators
  for (int blk = blockIdx.x; blk < 33792; blk += 2048) {
    if (blk < 32768) {
      const int id = ids[blk];
      float4 v = *(const float4*)&W[(size_t)id * 1024 + t * 4];
      ushort4 o; o.x = f2bf(v.x); o.y = f2bf(v.y); o.z = f2bf(v.z); o.w = f2bf(v.w);
      *(ushort4*)&swb[(size_t)blk * 1024 + t * 4] = o;
      if (t == 0) sbg[blk] = bb[id];
    } else {
      const int r = blk - 32768;
      float4 v = *(const float4*)&x[(size_t)r * 1024 + t * 4];
      ushort4 o; o.x = f2bf(v.x); o.y = f2bf(v.y); o.z = f2bf(v.z); o.w = f2bf(v.w);
      *(ushort4*)&xb[(size_t)r * 1024 + t * 4] = o;
    }
  }
}

// ---- swizzled staging: 128x32 bf16 tile, global -> LDS ---------------------
__device__ __forceinline__ void stage_sw(const unsigned short* g, int lda,
                                         unsigned short* l, int t) {
#pragma unroll
  for (int i = 0; i < 2; ++i) {
    const int idx = i * 256 + t;
    const int row = idx >> 2;
    const int c = (idx & 3) ^ ((row >> 1) & 3);
    const unsigned short* gp = g + (size_t)row * lda + c * 8;
    __builtin_amdgcn_global_load_lds(AS1C(gp), AS3(l + idx * 8), 16, 0, 0);
  }
}

__device__ __forceinline__ void stage_rp(const float* __restrict__ rp, int k0,
                                         unsigned short* l, int t) {
#pragma unroll
  for (int ii = 0; ii < 4; ++ii) {
    int idx = ii * 256 + t;            // 0..1023
    int kk = idx & 31, c4 = idx >> 5;  // kk fast -> conflict-free LDS writes
    float4 v = *(const float4*)&rp[(size_t)(k0 + kk) * 128 + c4 * 4];
    l[(c4 * 4 + 0) * 32 + kk] = f2bf(v.x);
    l[(c4 * 4 + 1) * 32 + kk] = f2bf(v.y);
    l[(c4 * 4 + 2) * 32 + kk] = f2bf(v.z);
    l[(c4 * 4 + 3) * 32 + kk] = f2bf(v.w);
  }
}

// ---- K3: wp = [W[ids],b[ids]] @ rp ; wn = normalize rows ; bf16 ------------
__global__ __launch_bounds__(256) void k_wn(
    const unsigned short* __restrict__ swb, const float* __restrict__ rp,
    const float* __restrict__ sbg, unsigned short* __restrict__ wnb) {
  __shared__ unsigned short As[2][128 * 32];
  __shared__ unsigned short Bs[2][128 * 32];
  __shared__ float nbuf[2][128];
  const int t = threadIdx.x;
  const int r0 = blockIdx.x * 128;
  const unsigned short* Ag = swb + (size_t)r0 * 1024;
  f32x4 acc[4][4];
#pragma unroll
  for (int m = 0; m < 4; ++m)
#pragma unroll
    for (int n = 0; n < 4; ++n) acc[m][n] = f32x4{0.f, 0.f, 0.f, 0.f};
  stage_sw(Ag, 1024, &As[0][0], t);
  stage_rp(rp, 0, &Bs[0][0], t);
  const int l = t & 63, w = t >> 6, wm = w >> 1, wn = w & 1;
  const int lr = l & 15, lk = l >> 4;
  const int kch = lk * 8;
  const int ach = (lk ^ ((lr >> 1) & 3)) * 8;  // swizzled chunk for A reads
  for (int kt = 0; kt < 32; ++kt) {
    const int cur = kt & 1;
    __syncthreads();
    if (kt + 1 < 32) {
      stage_sw(Ag + (kt + 1) * 32, 1024, &As[cur ^ 1][0], t);
      stage_rp(rp, (kt + 1) * 32, &Bs[cur ^ 1][0], t);
    }
    short8v a[4], b[4];
#pragma unroll
    for (int m = 0; m < 4; ++m) a[m] = *(const short8v*)&As[cur][(wm * 64 + m * 16 + lr) * 32 + ach];
#pragma unroll
    for (int n = 0; n < 4; ++n) b[n] = *(const short8v*)&Bs[cur][(wn * 64 + n * 16 + lr) * 32 + kch];
#pragma unroll
    for (int m = 0; m < 4; ++m)
#pragma unroll
      for (int n = 0; n < 4; ++n)
        acc[m][n] = __builtin_amdgcn_mfma_f32_16x16x32_bf16(a[m], b[n], acc[m][n], 0, 0, 0);
  }
  const float* rpl = rp + (size_t)1024 * 128;
  float sb_r[4][4];
#pragma unroll
  for (int m = 0; m < 4; ++m)
#pragma unroll
    for (int i = 0; i < 4; ++i)
      sb_r[m][i] = sbg[r0 + wm * 64 + m * 16 + lk * 4 + i];
#pragma unroll
  for (int n = 0; n < 4; ++n) {
    const int gc = wn * 64 + n * 16 + lr;
    const float rl = rpl[gc];
#pragma unroll
    for (int m = 0; m < 4; ++m)
#pragma unroll
      for (int i = 0; i < 4; ++i) acc[m][n][i] += sb_r[m][i] * rl;
  }
#pragma unroll
  for (int m = 0; m < 4; ++m)
#pragma unroll
    for (int i = 0; i < 4; ++i) {
      float s = 0.f;
#pragma unroll
      for (int n = 0; n < 4; ++n) s += acc[m][n][i] * acc[m][n][i];
#pragma unroll
      for (int msk = 1; msk < 16; msk <<= 1) s += __shfl_xor(s, msk, 64);
      if (lr == 0) nbuf[wn][wm * 64 + m * 16 + lk * 4 + i] = s;
    }
  __syncthreads();
#pragma unroll
  for (int m = 0; m < 4; ++m)
#pragma unroll
    for (int i = 0; i < 4; ++i) {
      const int lrow = wm * 64 + m * 16 + lk * 4 + i;
      const float n2 = nbuf[0][lrow] + nbuf[1][lrow];
      const float sc = 1.f / fmaxf(sqrtf(n2), 1e-6f);
#pragma unroll
      for (int n = 0; n < 4; ++n) {
        const int gc = wn * 64 + n * 16 + lr;
        wnb[(size_t)(r0 + lrow) * 128 + gc] = f2bf(acc[m][n][i] * sc);
      }
    }
}

// ---- K4: main GEMM  logits = xb @ swb^T + sb  (128x128, R9-proven) ---------
__global__ __launch_bounds__(256) void k_gemm_main(
    const unsigned short* __restrict__ A, const unsigned short* __restrict__ B,
    const float* __restrict__ sbg, float* __restrict__ out) {
  __shared__ unsigned short As[2][128 * 32];
  __shared__ unsigned short Bs[2][128 * 32];
  const int t = threadIdx.x;
  // 2048 blocks, 8 XCDs, 256 logical tiles per XCD (nwg%8==0 -> bijective)
  const int lb = (blockIdx.x & 7) * 256 + (blockIdx.x >> 3);
  const int bm = lb & 7, bn = lb >> 3;
  const unsigned short* Ag = A + (size_t)bm * 128 * 1024;
  const unsigned short* Bg = B + (size_t)bn * 128 * 1024;
  f32x4 acc[2][8];
#pragma unroll
  for (int m = 0; m < 2; ++m)
#pragma unroll
    for (int n = 0; n < 8; ++n) acc[m][n] = f32x4{0.f, 0.f, 0.f, 0.f};
  stage_sw(Ag, 1024, &As[0][0], t);
  stage_sw(Bg, 1024, &Bs[0][0], t);
  const int l = t & 63, w = t >> 6;        // wave w owns rows w*32..w*32+31
  const int lr = l & 15, lk = l >> 4;
  const int ach = (lk ^ ((lr >> 1) & 3)) * 8;  // swizzled chunk (per-lane const)
  for (int kt = 0; kt < 32; ++kt) {
    const int cur = kt & 1;
    __syncthreads();
    if (kt + 1 < 32) {
      stage_sw(Ag + (kt + 1) * 32, 1024, &As[cur ^ 1][0], t);
      stage_sw(Bg + (kt + 1) * 32, 1024, &Bs[cur ^ 1][0], t);
    }
    short8v a[2], b[8];
#pragma unroll
    for (int m = 0; m < 2; ++m)
      a[m] = *(const short8v*)&As[cur][(w * 32 + m * 16 + lr) * 32 + ach];
#pragma unroll
    for (int n = 0; n < 8; ++n)
      b[n] = *(const short8v*)&Bs[cur][(n * 16 + lr) * 32 + ach];
#pragma unroll
    for (int m = 0; m < 2; ++m)
#pragma unroll
      for (int n = 0; n < 8; ++n)
        acc[m][n] = __builtin_amdgcn_mfma_f32_16x16x32_bf16(a[m], b[n], acc[m][n], 0, 0, 0);
  }
  const int rb = bm * 128 + w * 32, cb = bn * 128;
#pragma unroll
  for (int n = 0; n < 8; ++n) {
    const int gc = cb + n * 16 + lr;
    const float bias = sbg[gc];
#pragma unroll
    for (int m = 0; m < 2; ++m)
#pragma unroll
      for (int i = 0; i < 4; ++i) {
        const int gr = rb + m * 16 + lk * 4 + i;
        out[(size_t)gr * 32768 + gc] = acc[m][n][i] + bias;
      }
  }
}

// ---- K5: single-HBM-pass bf16-exact kthvalue (1024 thr -> 32 waves/CU) -----
__global__ __launch_bounds__(1024) void k_hist(
    const float* __restrict__ logits, const float* __restrict__ sbg,
    float* __restrict__ scal) {
  __shared__ unsigned short rowm[32768];  // 64 KiB mapped keys
  __shared__ unsigned hist[2048];
  __shared__ unsigned scanbuf[1024];
  __shared__ unsigned hsub[64];
  __shared__ int res[4];
  const int t = threadIdx.x, row = blockIdx.x;
  for (int i = t; i < 2048; i += 1024) hist[i] = 0u;
  if (t < 64) hsub[t] = 0u;
  __syncthreads();
  const float* lp = logits + (size_t)row * 32768;
  for (int c = t * 4; c < 32768; c += 4096) {
    const float4 lv = *(const float4*)&lp[c];
    const float4 sb4 = *(const float4*)&sbg[c];
    const float pr[4] = {lv.x - sb4.x, lv.y - sb4.y, lv.z - sb4.z, lv.w - sb4.w};
    unsigned short mm[4];
#pragma unroll
    for (int j = 0; j < 4; ++j) {
      const unsigned short bbf = f2bf(pr[j]);
      const unsigned m = (bbf & 0x8000u) ? (0xFFFFu ^ (unsigned)bbf)
                                         : ((unsigned)bbf | 0x8000u);
      mm[j] = (unsigned short)m;
      atomicAdd(&hist[m >> 5], 1u);
    }
    *(ushort4*)&rowm[c] = make_ushort4(mm[0], mm[1], mm[2], mm[3]);
  }
  __syncthreads();
  {  // 2048-bin scan over 1024 threads (2 bins each)
    unsigned s = hist[t * 2] + hist[t * 2 + 1];
    scanbuf[t] = s;
    __syncthreads();
    unsigned x = s;
    for (int off = 1; off < 1024; off <<= 1) {
      unsigned y = (t >= off) ? scanbuf[t - off] : 0u;
      __syncthreads();
      x += y; scanbuf[t] = x;
      __syncthreads();
    }
    unsigned run = x - s;
    const unsigned K1R = 32734u, K2R = 16383u;  // 0-indexed kth ranks
#pragma unroll
    for (int j = 0; j < 2; ++j) {
      unsigned c = hist[t * 2 + j];
      if (K1R >= run && K1R < run + c) { res[0] = t * 2 + j; res[1] = (int)(K1R - run); }
      if (K2R >= run && K2R < run + c) { res[2] = t * 2 + j; res[3] = (int)(K2R - run); }
      run += c;
    }
  }
  __syncthreads();
  const unsigned bin1 = (unsigned)res[0], r1 = (unsigned)res[1];
  const unsigned bin2 = (unsigned)res[2], r2 = (unsigned)res[3];
  for (int c = t; c < 32768; c += 1024) {
    const unsigned m = rowm[c];
    const unsigned bq = m >> 5;
    if (bq == bin1) atomicAdd(&hsub[m & 31], 1u);
    if (bq == bin2) atomicAdd(&hsub[32 + (m & 31)], 1u);
  }
  __syncthreads();
  if (t == 0) {
    unsigned a_ = 0; int sub1 = 31;
    for (int j = 0; j < 32; ++j) { if (r1 < a_ + hsub[j]) { sub1 = j; break; } a_ += hsub[j]; }
    a_ = 0; int sub2 = 31;
    for (int j = 0; j < 32; ++j) { if (r2 < a_ + hsub[32 + j]) { sub2 = j; break; } a_ += hsub[32 + j]; }
    const unsigned m1 = (bin1 << 5) | (unsigned)sub1;
    const unsigned m2 = (bin2 << 5) | (unsigned)sub2;
    const float kv1 = bf2f((unsigned short)((m1 & 0x8000u) ? (m1 & 0x7FFFu) : (0xFFFFu ^ m1)));
    const float kv2 = bf2f((unsigned short)((m2 & 0x8000u) ? (m2 & 0x7FFFu) : (0xFFFFu ^ m2)));
    atomicAdd(&scal[0], kv1);   // kth-value sums; k_sim divides by 1024
    atomicAdd(&scal[1], kv2);
  }
}

// ---- K7: sim = qn @ wn^T fused with masked sums ----------------------------
// ILP-fixed: sbg float4 hoisted (per-thread col is loop-invariant),
// __launch_bounds__(256,5) -> ~100 VGPR for deep load pipelining,
// LDS exactly 32 KiB (red unioned) -> 5 blocks/CU.
__global__ __launch_bounds__(256, 5) void k_sim(
    const unsigned short* __restrict__ A, const unsigned short* __restrict__ B,
    const float* __restrict__ logits, const float* __restrict__ sbg,
    const float* __restrict__ scal, float4* __restrict__ part) {
  __shared__ unsigned short smem[128 * 128];  // 32 KiB: As/Bs -> simb -> red
  unsigned short* As = smem;
  unsigned short* Bs = smem + 128 * 32;
  unsigned short* simb = smem;
  float* red = (float*)smem;                  // aliases simb after final barrier
  const int t = threadIdx.x;
  const int bm = blockIdx.x & 7, bn = blockIdx.x >> 3;
  const unsigned short* Ag = A + (size_t)bm * 128 * 128;
  const unsigned short* Bg = B + (size_t)bn * 128 * 128;
  f32x4 acc[4][4];
#pragma unroll
  for (int m = 0; m < 4; ++m)
#pragma unroll
    for (int n = 0; n < 4; ++n) acc[m][n] = f32x4{0.f, 0.f, 0.f, 0.f};
  const int l = t & 63, w = t >> 6, wm = w >> 1, wn = w & 1;
  const int lr = l & 15, lk = l >> 4;
  const int ach = (lk ^ ((lr >> 1) & 3)) * 8;
  for (int kt = 0; kt < 4; ++kt) {
    stage_sw(Ag + kt * 32, 128, As, t);
    stage_sw(Bg + kt * 32, 128, Bs, t);
    __syncthreads();
    short8v a[4], b[4];
#pragma unroll
    for (int m = 0; m < 4; ++m) a[m] = *(const short8v*)&As[(wm * 64 + m * 16 + lr) * 32 + ach];
#pragma unroll
    for (int n = 0; n < 4; ++n) b[n] = *(const short8v*)&Bs[(wn * 64 + n * 16 + lr) * 32 + ach];
#pragma unroll
    for (int m = 0; m < 4; ++m)
#pragma unroll
      for (int n = 0; n < 4; ++n)
        acc[m][n] = __builtin_amdgcn_mfma_f32_16x16x32_bf16(a[m], b[n], acc[m][n], 0, 0, 0);
    __syncthreads();
  }
#pragma unroll
  for (int m = 0; m < 4; ++m)
#pragma unroll
    for (int n = 0; n < 4; ++n) {
      const int col = wn * 64 + n * 16 + lr;
#pragma unroll
      for (int i = 0; i < 4; ++i) {
        const int row = wm * 64 + m * 16 + lk * 4 + i;
        simb[row * 128 + col] = f2bf(acc[m][n][i]);
      }
    }
  __syncthreads();
  const float t1 = fmaxf(scal[0] * (1.f / 1024.f), 0.f);
  const float t2 = scal[1] * (1.f / 1024.f);
  const int rb0 = bm * 128, cb0 = bn * 128;
  // per-thread column is loop-invariant: c4 = t&31, rows = it*8 + (t>>5)
  const int c4 = t & 31, rbase = t >> 5;
  const float4 sb4 = *(const float4*)&sbg[cb0 + c4 * 4];
  float ps = 0.f, pc = 0.f, ns = 0.f, nc = 0.f;
#pragma unroll
  for (int it = 0; it < 16; ++it) {
    const int rr = it * 8 + rbase;
    const float4 lv = *(const float4*)&logits[(size_t)(rb0 + rr) * 32768 + cb0 + c4 * 4];
    const ushort4 sv = *(const ushort4*)&simb[rr * 128 + c4 * 4];
    const float pr[4] = {lv.x - sb4.x, lv.y - sb4.y, lv.z - sb4.z, lv.w - sb4.w};
    const float sm[4] = {bf2f(sv.x), bf2f(sv.y), bf2f(sv.z), bf2f(sv.w)};
#pragma unroll
    for (int j = 0; j < 4; ++j) {
      if (pr[j] > t1) { ps += sm[j]; pc += 1.f; }
      if (pr[j] < t2) { ns += sm[j]; nc += 1.f; }
    }
  }
#pragma unroll
  for (int m = 1; m < 64; m <<= 1) {
    ps += __shfl_xor(ps, m, 64); pc += __shfl_xor(pc, m, 64);
    ns += __shfl_xor(ns, m, 64); nc += __shfl_xor(nc, m, 64);
  }
  __syncthreads();  // all simb reads done before red aliases it
  if (l == 0) { red[w * 4 + 0] = ps; red[w * 4 + 1] = pc; red[w * 4 + 2] = ns; red[w * 4 + 3] = nc; }
  __syncthreads();
  if (t == 0) {
    float4 o;
    o.x = red[0] + red[4] + red[8]  + red[12];
    o.y = red[1] + red[5] + red[9]  + red[13];
    o.z = red[2] + red[6] + red[10] + red[14];
    o.w = red[3] + red[7] + red[11] + red[15];
    part[blockIdx.x] = o;
  }
}

// ---- K8: reduce per-block partials, finalize triplet loss ------------------
__global__ __launch_bounds__(256) void k_final(
    const float4* __restrict__ part, float* __restrict__ out) {
  __shared__ float red[4][4];
  const int t = threadIdx.x;
  float ps = 0.f, pc = 0.f, ns = 0.f, nc = 0.f;
  for (int i = t; i < 2048; i += 256) {
    float4 v = part[i];
    ps += v.x; pc += v.y; ns += v.z; nc += v.w;
  }
#pragma unroll
  for (int m = 1; m < 64; m <<= 1) {
    ps += __shfl_xor(ps, m, 64); pc += __shfl_xor(pc, m, 64);
    ns += __shfl_xor(ns, m, 64); nc += __shfl_xor(nc, m, 64);
  }
  const int w = t >> 6;
  if ((t & 63) == 0) { red[w][0] = ps; red[w][1] = pc; red[w][2] = ns; red[w][3] = nc; }
  __syncthreads();
  if (t == 0) {
    float tps = red[0][0] + red[1][0] + red[2][0] + red[3][0];
    float tpc = red[0][1] + red[1][1] + red[2][1] + red[3][1];
    float tns = red[0][2] + red[1][2] + red[2][2] + red[3][2];
    float tnc = red[0][3] + red[1][3] + red[2][3] + red[3][3];
    float sp = tps / fmaxf(tpc, 1.f);
    float sn = tns / fmaxf(tnc, 1.f);
    out[33554432] = fmaxf(sn - sp + 1.f, 0.f);
  }
}

// ---------------------------------------------------------------------------
extern "C" void kernel_launch(void* const* d_in, const int* in_sizes, int n_in,
                              void* d_out, int out_size, void* d_ws, size_t ws_size,
                              hipStream_t stream) {
  const float* x  = (const float*)d_in[0];
  const float* W  = (const float*)d_in[1];
  const float* b  = (const float*)d_in[2];
  const float* rp = (const float*)d_in[3];
  const int*  ids = (const int*)d_in[4];
  float* out = (float*)d_out;
  char* ws = (char*)d_ws;

  unsigned short* swb = (unsigned short*)(ws);                 // 64 MiB
  unsigned short* xb  = (unsigned short*)(ws + 67108864);      //  2 MiB
  float*          sbg = (float*)(ws + 69206016);               // 128 KiB
  unsigned short* qnb = (unsigned short*)(ws + 69337088);      // 256 KiB
  unsigned short* wnb = (unsigned short*)(ws + 69599232);      //  8 MiB
  float*         scal = (float*)(ws + 78012416);               // 8 floats
  float4*        part = (float4*)(ws + 78016512);              // 32 KiB

  k_gather   <<<2304,  256, 0, stream>>>(W, b, x, ids, swb, sbg, xb, scal, rp, qnb);
  k_wn       <<<256,   256, 0, stream>>>(swb, rp, sbg, wnb);
  k_gemm_main<<<2048,  256, 0, stream>>>(xb, swb, sbg, out);
  k_hist     <<<1024, 1024, 0, stream>>>(out, sbg, scal);
  k_sim      <<<2048,  256, 0, stream>>>(qnb, wnb, out, sbg, scal, part);
  k_final    <<<1,     256, 0, stream>>>(part, out);
}

// Round 16
// 306.184 us; speedup vs baseline: 1.4118x; 1.0548x over previous
//
#include <hip/hip_runtime.h>

// ---------------------------------------------------------------------------
// LSHSampledLayer: logits = x @ W[ids]^T + b[ids]; kth-value thresholds;
// masked-mean cosine-sim triplet loss on random projections.
// N=1024, D=K=1024, C=S=32768, P=128.
// ---------------------------------------------------------------------------

using short8v = __attribute__((ext_vector_type(8))) short;
using f32x4   = __attribute__((ext_vector_type(4))) float;

#define AS1C(p) ((const __attribute__((address_space(1))) void*)(p))
#define AS3(p)  ((__attribute__((address_space(3))) void*)(p))

__device__ __forceinline__ unsigned short f2bf(float f) {
  union { float f; unsigned u; } v; v.f = f;
  unsigned u = v.u;
  return (unsigned short)((u + 0x7FFFu + ((u >> 16) & 1u)) >> 16);  // RNE
}
__device__ __forceinline__ float bf2f(unsigned short s) {
  return __uint_as_float(((unsigned)s) << 16);
}

// ---- K1: gather W[ids]->bf16, b[ids]->f32, cast x->bf16; + qn blocks -------
__global__ __launch_bounds__(256) void k_gather(
    const float* __restrict__ W, const float* __restrict__ bb,
    const float* __restrict__ x, const int* __restrict__ ids,
    unsigned short* __restrict__ swb, float* __restrict__ sbg,
    unsigned short* __restrict__ xb, float* __restrict__ scal,
    const float* __restrict__ rp, unsigned short* __restrict__ qnb) {
  const int t = threadIdx.x;
  if (blockIdx.x >= 2048) {  // ---- qn part: 256 blocks ----
    __shared__ float xs[4][1024];
    __shared__ float part[4][2];
    const int r0 = (blockIdx.x - 2048) * 4;
#pragma unroll
    for (int i = 0; i < 4; ++i) {
      int idx = i * 256 + t, rr = idx >> 8, c4 = idx & 255;
      *(float4*)&xs[rr][c4 * 4] = *(const float4*)&x[(size_t)(r0 + rr) * 1024 + c4 * 4];
    }
    __syncthreads();
    const int col = t & 127, rsel = t >> 7;
    float a0 = 0.f, a1 = 0.f;
    for (int k = 0; k < 1024; k += 4) {
      float4 xa = *(const float4*)&xs[rsel][k];
      float4 xbv = *(const float4*)&xs[rsel + 2][k];
      float av[4] = {xa.x, xa.y, xa.z, xa.w};
      float bv[4] = {xbv.x, xbv.y, xbv.z, xbv.w};
#pragma unroll
      for (int j = 0; j < 4; ++j) {
        float rv = rp[(size_t)(k + j) * 128 + col];
        a0 += av[j] * rv;
        a1 += bv[j] * rv;
      }
    }
    { float rv = rp[(size_t)1024 * 128 + col]; a0 += rv; a1 += rv; }
    float s0 = a0 * a0, s1 = a1 * a1;
#pragma unroll
    for (int m = 1; m < 64; m <<= 1) { s0 += __shfl_xor(s0, m, 64); s1 += __shfl_xor(s1, m, 64); }
    if ((t & 63) == 0) { part[t >> 6][0] = s0; part[t >> 6][1] = s1; }
    __syncthreads();
    float n0 = part[2 * rsel][0] + part[2 * rsel + 1][0];
    float n1 = part[2 * rsel][1] + part[2 * rsel + 1][1];
    qnb[(size_t)(r0 + rsel) * 128 + col]     = f2bf(a0 / fmaxf(sqrtf(n0), 1e-6f));
    qnb[(size_t)(r0 + rsel + 2) * 128 + col] = f2bf(a1 / fmaxf(sqrtf(n1), 1e-6f));
    return;
  }
  if (blockIdx.x == 0 && t < 8) scal[t] = 0.f;  // zero accumulators
  for (int blk = blockIdx.x; blk < 33792; blk += 2048) {
    if (blk < 32768) {
      const int id = ids[blk];
      float4 v = *(const float4*)&W[(size_t)id * 1024 + t * 4];
      ushort4 o; o.x = f2bf(v.x); o.y = f2bf(v.y); o.z = f2bf(v.z); o.w = f2bf(v.w);
      *(ushort4*)&swb[(size_t)blk * 1024 + t * 4] = o;
      if (t == 0) sbg[blk] = bb[id];
    } else {
      const int r = blk - 32768;
      float4 v = *(const float4*)&x[(size_t)r * 1024 + t * 4];
      ushort4 o; o.x = f2bf(v.x); o.y = f2bf(v.y); o.z = f2bf(v.z); o.w = f2bf(v.w);
      *(ushort4*)&xb[(size_t)r * 1024 + t * 4] = o;
    }
  }
}

// ---- swizzled staging: 128x32 bf16 tile, global -> LDS ---------------------
__device__ __forceinline__ void stage_sw(const unsigned short* g, int lda,
                                         unsigned short* l, int t) {
#pragma unroll
  for (int i = 0; i < 2; ++i) {
    const int idx = i * 256 + t;
    const int row = idx >> 2;
    const int c = (idx & 3) ^ ((row >> 1) & 3);
    const unsigned short* gp = g + (size_t)row * lda + c * 8;
    __builtin_amdgcn_global_load_lds(AS1C(gp), AS3(l + idx * 8), 16, 0, 0);
  }
}

__device__ __forceinline__ void stage_rp(const float* __restrict__ rp, int k0,
                                         unsigned short* l, int t) {
#pragma unroll
  for (int ii = 0; ii < 4; ++ii) {
    int idx = ii * 256 + t;            // 0..1023
    int kk = idx & 31, c4 = idx >> 5;  // kk fast -> conflict-free LDS writes
    float4 v = *(const float4*)&rp[(size_t)(k0 + kk) * 128 + c4 * 4];
    l[(c4 * 4 + 0) * 32 + kk] = f2bf(v.x);
    l[(c4 * 4 + 1) * 32 + kk] = f2bf(v.y);
    l[(c4 * 4 + 2) * 32 + kk] = f2bf(v.z);
    l[(c4 * 4 + 3) * 32 + kk] = f2bf(v.w);
  }
}

// ---- K3: wp = [W[ids],b[ids]] @ rp ; wn = normalize rows ; bf16 ------------
__global__ __launch_bounds__(256) void k_wn(
    const unsigned short* __restrict__ swb, const float* __restrict__ rp,
    const float* __restrict__ sbg, unsigned short* __restrict__ wnb) {
  __shared__ unsigned short As[2][128 * 32];
  __shared__ unsigned short Bs[2][128 * 32];
  __shared__ float nbuf[2][128];
  const int t = threadIdx.x;
  const int r0 = blockIdx.x * 128;
  const unsigned short* Ag = swb + (size_t)r0 * 1024;
  f32x4 acc[4][4];
#pragma unroll
  for (int m = 0; m < 4; ++m)
#pragma unroll
    for (int n = 0; n < 4; ++n) acc[m][n] = f32x4{0.f, 0.f, 0.f, 0.f};
  stage_sw(Ag, 1024, &As[0][0], t);
  stage_rp(rp, 0, &Bs[0][0], t);
  const int l = t & 63, w = t >> 6, wm = w >> 1, wn = w & 1;
  const int lr = l & 15, lk = l >> 4;
  const int kch = lk * 8;
  const int ach = (lk ^ ((lr >> 1) & 3)) * 8;  // swizzled chunk for A reads
  for (int kt = 0; kt < 32; ++kt) {
    const int cur = kt & 1;
    __syncthreads();
    if (kt + 1 < 32) {
      stage_sw(Ag + (kt + 1) * 32, 1024, &As[cur ^ 1][0], t);
      stage_rp(rp, (kt + 1) * 32, &Bs[cur ^ 1][0], t);
    }
    short8v a[4], b[4];
#pragma unroll
    for (int m = 0; m < 4; ++m) a[m] = *(const short8v*)&As[cur][(wm * 64 + m * 16 + lr) * 32 + ach];
#pragma unroll
    for (int n = 0; n < 4; ++n) b[n] = *(const short8v*)&Bs[cur][(wn * 64 + n * 16 + lr) * 32 + kch];
#pragma unroll
    for (int m = 0; m < 4; ++m)
#pragma unroll
      for (int n = 0; n < 4; ++n)
        acc[m][n] = __builtin_amdgcn_mfma_f32_16x16x32_bf16(a[m], b[n], acc[m][n], 0, 0, 0);
  }
  const float* rpl = rp + (size_t)1024 * 128;
  float sb_r[4][4];
#pragma unroll
  for (int m = 0; m < 4; ++m)
#pragma unroll
    for (int i = 0; i < 4; ++i)
      sb_r[m][i] = sbg[r0 + wm * 64 + m * 16 + lk * 4 + i];
#pragma unroll
  for (int n = 0; n < 4; ++n) {
    const int gc = wn * 64 + n * 16 + lr;
    const float rl = rpl[gc];
#pragma unroll
    for (int m = 0; m < 4; ++m)
#pragma unroll
      for (int i = 0; i < 4; ++i) acc[m][n][i] += sb_r[m][i] * rl;
  }
#pragma unroll
  for (int m = 0; m < 4; ++m)
#pragma unroll
    for (int i = 0; i < 4; ++i) {
      float s = 0.f;
#pragma unroll
      for (int n = 0; n < 4; ++n) s += acc[m][n][i] * acc[m][n][i];
#pragma unroll
      for (int msk = 1; msk < 16; msk <<= 1) s += __shfl_xor(s, msk, 64);
      if (lr == 0) nbuf[wn][wm * 64 + m * 16 + lk * 4 + i] = s;
    }
  __syncthreads();
#pragma unroll
  for (int m = 0; m < 4; ++m)
#pragma unroll
    for (int i = 0; i < 4; ++i) {
      const int lrow = wm * 64 + m * 16 + lk * 4 + i;
      const float n2 = nbuf[0][lrow] + nbuf[1][lrow];
      const float sc = 1.f / fmaxf(sqrtf(n2), 1e-6f);
#pragma unroll
      for (int n = 0; n < 4; ++n) {
        const int gc = wn * 64 + n * 16 + lr;
        wnb[(size_t)(r0 + lrow) * 128 + gc] = f2bf(acc[m][n][i] * sc);
      }
    }
}

// ---- K4: main GEMM  logits = xb @ swb^T + sb  (128x128, R9-proven) ---------
__global__ __launch_bounds__(256) void k_gemm_main(
    const unsigned short* __restrict__ A, const unsigned short* __restrict__ B,
    const float* __restrict__ sbg, float* __restrict__ out) {
  __shared__ unsigned short As[2][128 * 32];
  __shared__ unsigned short Bs[2][128 * 32];
  const int t = threadIdx.x;
  // 2048 blocks, 8 XCDs, 256 logical tiles per XCD (nwg%8==0 -> bijective)
  const int lb = (blockIdx.x & 7) * 256 + (blockIdx.x >> 3);
  const int bm = lb & 7, bn = lb >> 3;
  const unsigned short* Ag = A + (size_t)bm * 128 * 1024;
  const unsigned short* Bg = B + (size_t)bn * 128 * 1024;
  f32x4 acc[2][8];
#pragma unroll
  for (int m = 0; m < 2; ++m)
#pragma unroll
    for (int n = 0; n < 8; ++n) acc[m][n] = f32x4{0.f, 0.f, 0.f, 0.f};
  stage_sw(Ag, 1024, &As[0][0], t);
  stage_sw(Bg, 1024, &Bs[0][0], t);
  const int l = t & 63, w = t >> 6;        // wave w owns rows w*32..w*32+31
  const int lr = l & 15, lk = l >> 4;
  const int ach = (lk ^ ((lr >> 1) & 3)) * 8;  // swizzled chunk (per-lane const)
  for (int kt = 0; kt < 32; ++kt) {
    const int cur = kt & 1;
    __syncthreads();
    if (kt + 1 < 32) {
      stage_sw(Ag + (kt + 1) * 32, 1024, &As[cur ^ 1][0], t);
      stage_sw(Bg + (kt + 1) * 32, 1024, &Bs[cur ^ 1][0], t);
    }
    short8v a[2], b[8];
#pragma unroll
    for (int m = 0; m < 2; ++m)
      a[m] = *(const short8v*)&As[cur][(w * 32 + m * 16 + lr) * 32 + ach];
#pragma unroll
    for (int n = 0; n < 8; ++n)
      b[n] = *(const short8v*)&Bs[cur][(n * 16 + lr) * 32 + ach];
#pragma unroll
    for (int m = 0; m < 2; ++m)
#pragma unroll
      for (int n = 0; n < 8; ++n)
        acc[m][n] = __builtin_amdgcn_mfma_f32_16x16x32_bf16(a[m], b[n], acc[m][n], 0, 0, 0);
  }
  const int rb = bm * 128 + w * 32, cb = bn * 128;
#pragma unroll
  for (int n = 0; n < 8; ++n) {
    const int gc = cb + n * 16 + lr;
    const float bias = sbg[gc];
#pragma unroll
    for (int m = 0; m < 2; ++m)
#pragma unroll
      for (int i = 0; i < 4; ++i) {
        const int gr = rb + m * 16 + lk * 4 + i;
        out[(size_t)gr * 32768 + gc] = acc[m][n][i] + bias;
      }
  }
}

// ---- K5: single-HBM-pass bf16-exact kthvalue (1024 thr -> 32 waves/CU) -----
__global__ __launch_bounds__(1024) void k_hist(
    const float* __restrict__ logits, const float* __restrict__ sbg,
    float* __restrict__ scal) {
  __shared__ unsigned short rowm[32768];  // 64 KiB mapped keys
  __shared__ unsigned hist[2048];
  __shared__ unsigned scanbuf[1024];
  __shared__ unsigned hsub[64];
  __shared__ int res[4];
  const int t = threadIdx.x, row = blockIdx.x;
  for (int i = t; i < 2048; i += 1024) hist[i] = 0u;
  if (t < 64) hsub[t] = 0u;
  __syncthreads();
  const float* lp = logits + (size_t)row * 32768;
  for (int c = t * 4; c < 32768; c += 4096) {
    const float4 lv = *(const float4*)&lp[c];
    const float4 sb4 = *(const float4*)&sbg[c];
    const float pr[4] = {lv.x - sb4.x, lv.y - sb4.y, lv.z - sb4.z, lv.w - sb4.w};
    unsigned short mm[4];
#pragma unroll
    for (int j = 0; j < 4; ++j) {
      const unsigned short bbf = f2bf(pr[j]);
      const unsigned m = (bbf & 0x8000u) ? (0xFFFFu ^ (unsigned)bbf)
                                         : ((unsigned)bbf | 0x8000u);
      mm[j] = (unsigned short)m;
      atomicAdd(&hist[m >> 5], 1u);
    }
    *(ushort4*)&rowm[c] = make_ushort4(mm[0], mm[1], mm[2], mm[3]);
  }
  __syncthreads();
  {  // 2048-bin scan over 1024 threads (2 bins each)
    unsigned s = hist[t * 2] + hist[t * 2 + 1];
    scanbuf[t] = s;
    __syncthreads();
    unsigned x = s;
    for (int off = 1; off < 1024; off <<= 1) {
      unsigned y = (t >= off) ? scanbuf[t - off] : 0u;
      __syncthreads();
      x += y; scanbuf[t] = x;
      __syncthreads();
    }
    unsigned run = x - s;
    const unsigned K1R = 32734u, K2R = 16383u;  // 0-indexed kth ranks
#pragma unroll
    for (int j = 0; j < 2; ++j) {
      unsigned c = hist[t * 2 + j];
      if (K1R >= run && K1R < run + c) { res[0] = t * 2 + j; res[1] = (int)(K1R - run); }
      if (K2R >= run && K2R < run + c) { res[2] = t * 2 + j; res[3] = (int)(K2R - run); }
      run += c;
    }
  }
  __syncthreads();
  const unsigned bin1 = (unsigned)res[0], r1 = (unsigned)res[1];
  const unsigned bin2 = (unsigned)res[2], r2 = (unsigned)res[3];
  for (int c = t; c < 32768; c += 1024) {
    const unsigned m = rowm[c];
    const unsigned bq = m >> 5;
    if (bq == bin1) atomicAdd(&hsub[m & 31], 1u);
    if (bq == bin2) atomicAdd(&hsub[32 + (m & 31)], 1u);
  }
  __syncthreads();
  if (t == 0) {
    unsigned a_ = 0; int sub1 = 31;
    for (int j = 0; j < 32; ++j) { if (r1 < a_ + hsub[j]) { sub1 = j; break; } a_ += hsub[j]; }
    a_ = 0; int sub2 = 31;
    for (int j = 0; j < 32; ++j) { if (r2 < a_ + hsub[32 + j]) { sub2 = j; break; } a_ += hsub[32 + j]; }
    const unsigned m1 = (bin1 << 5) | (unsigned)sub1;
    const unsigned m2 = (bin2 << 5) | (unsigned)sub2;
    const float kv1 = bf2f((unsigned short)((m1 & 0x8000u) ? (m1 & 0x7FFFu) : (0xFFFFu ^ m1)));
    const float kv2 = bf2f((unsigned short)((m2 & 0x8000u) ? (m2 & 0x7FFFu) : (0xFFFFu ^ m2)));
    atomicAdd(&scal[0], kv1);   // kth-value sums; k_sim divides by 1024
    atomicAdd(&scal[1], kv2);
  }
}

// ---- K7: sim = qn @ wn^T fused with masked sums ----------------------------
// Restructured: A fragments global->reg (qnb is L2-resident, 16 independent
// loads); B tile staged ONCE as 4 swizzled [128][32] sub-tiles (one drain +
// one barrier instead of 4); then 64 MFMA; simb unions over the B LDS.
__global__ __launch_bounds__(256) void k_sim(
    const unsigned short* __restrict__ A, const unsigned short* __restrict__ B,
    const float* __restrict__ logits, const float* __restrict__ sbg,
    const float* __restrict__ scal, float4* __restrict__ part) {
  __shared__ unsigned short smem[128 * 128];  // 32 KiB: Bs4[4][128*32] -> simb -> red
  unsigned short* simb = smem;
  float* red = (float*)smem;
  const int t = threadIdx.x;
  const int bm = blockIdx.x & 7, bn = blockIdx.x >> 3;
  const unsigned short* Ag = A + (size_t)bm * 128 * 128;
  const unsigned short* Bg = B + (size_t)bn * 128 * 128;
  const int l = t & 63, w = t >> 6, wm = w >> 1, wn = w & 1;
  const int lr = l & 15, lk = l >> 4;
  const int ach = (lk ^ ((lr >> 1) & 3)) * 8;
  // stage whole B tile (4 swizzled sub-tiles, 8 global_load_lds issued at once)
#pragma unroll
  for (int kt = 0; kt < 4; ++kt)
    stage_sw(Bg + kt * 32, 128, &smem[kt * 4096], t);
  // A fragments direct to registers (16 independent 16B loads, L2-hot)
  short8v af[4][4];
#pragma unroll
  for (int m = 0; m < 4; ++m)
#pragma unroll
    for (int kt = 0; kt < 4; ++kt)
      af[m][kt] = *(const short8v*)&Ag[(size_t)(wm * 64 + m * 16 + lr) * 128 + kt * 32 + lk * 8];
  f32x4 acc[4][4];
#pragma unroll
  for (int m = 0; m < 4; ++m)
#pragma unroll
    for (int n = 0; n < 4; ++n) acc[m][n] = f32x4{0.f, 0.f, 0.f, 0.f};
  __syncthreads();  // B tile landed (compiler inserts vmcnt before barrier)
#pragma unroll
  for (int kt = 0; kt < 4; ++kt) {
    short8v b[4];
#pragma unroll
    for (int n = 0; n < 4; ++n)
      b[n] = *(const short8v*)&smem[kt * 4096 + (wn * 64 + n * 16 + lr) * 32 + ach];
#pragma unroll
    for (int m = 0; m < 4; ++m)
#pragma unroll
      for (int n = 0; n < 4; ++n)
        acc[m][n] = __builtin_amdgcn_mfma_f32_16x16x32_bf16(af[m][kt], b[n], acc[m][n], 0, 0, 0);
  }
  __syncthreads();  // all B reads done before simb overwrites smem
#pragma unroll
  for (int m = 0; m < 4; ++m)
#pragma unroll
    for (int n = 0; n < 4; ++n) {
      const int col = wn * 64 + n * 16 + lr;
#pragma unroll
      for (int i = 0; i < 4; ++i) {
        const int row = wm * 64 + m * 16 + lk * 4 + i;
        simb[row * 128 + col] = f2bf(acc[m][n][i]);
      }
    }
  __syncthreads();
  const float t1 = fmaxf(scal[0] * (1.f / 1024.f), 0.f);
  const float t2 = scal[1] * (1.f / 1024.f);
  const int rb0 = bm * 128, cb0 = bn * 128;
  const int c4 = t & 31, rbase = t >> 5;   // per-thread col is loop-invariant
  const float4 sb4 = *(const float4*)&sbg[cb0 + c4 * 4];
  float ps = 0.f, pc = 0.f, ns = 0.f, nc = 0.f;
#pragma unroll
  for (int it = 0; it < 16; ++it) {
    const int rr = it * 8 + rbase;
    const float4 lv = *(const float4*)&logits[(size_t)(rb0 + rr) * 32768 + cb0 + c4 * 4];
    const ushort4 sv = *(const ushort4*)&simb[rr * 128 + c4 * 4];
    const float pr[4] = {lv.x - sb4.x, lv.y - sb4.y, lv.z - sb4.z, lv.w - sb4.w};
    const float sm[4] = {bf2f(sv.x), bf2f(sv.y), bf2f(sv.z), bf2f(sv.w)};
#pragma unroll
    for (int j = 0; j < 4; ++j) {
      if (pr[j] > t1) { ps += sm[j]; pc += 1.f; }
      if (pr[j] < t2) { ns += sm[j]; nc += 1.f; }
    }
  }
#pragma unroll
  for (int m = 1; m < 64; m <<= 1) {
    ps += __shfl_xor(ps, m, 64); pc += __shfl_xor(pc, m, 64);
    ns += __shfl_xor(ns, m, 64); nc += __shfl_xor(nc, m, 64);
  }
  __syncthreads();  // all simb reads done before red aliases it
  if (l == 0) { red[w * 4 + 0] = ps; red[w * 4 + 1] = pc; red[w * 4 + 2] = ns; red[w * 4 + 3] = nc; }
  __syncthreads();
  if (t == 0) {
    float4 o;
    o.x = red[0] + red[4] + red[8]  + red[12];
    o.y = red[1] + red[5] + red[9]  + red[13];
    o.z = red[2] + red[6] + red[10] + red[14];
    o.w = red[3] + red[7] + red[11] + red[15];
    part[blockIdx.x] = o;
  }
}

// ---- K8: reduce per-block partials, finalize triplet loss ------------------
__global__ __launch_bounds__(256) void k_final(
    const float4* __restrict__ part, float* __restrict__ out) {
  __shared__ float red[4][4];
  const int t = threadIdx.x;
  float ps = 0.f, pc = 0.f, ns = 0.f, nc = 0.f;
  for (int i = t; i < 2048; i += 256) {
    float4 v = part[i];
    ps += v.x; pc += v.y; ns += v.z; nc += v.w;
  }
#pragma unroll
  for (int m = 1; m < 64; m <<= 1) {
    ps += __shfl_xor(ps, m, 64); pc += __shfl_xor(pc, m, 64);
    ns += __shfl_xor(ns, m, 64); nc += __shfl_xor(nc, m, 64);
  }
  const int w = t >> 6;
  if ((t & 63) == 0) { red[w][0] = ps; red[w][1] = pc; red[w][2] = ns; red[w][3] = nc; }
  __syncthreads();
  if (t == 0) {
    float tps = red[0][0] + red[1][0] + red[2][0] + red[3][0];
    float tpc = red[0][1] + red[1][1] + red[2][1] + red[3][1];
    float tns = red[0][2] + red[1][2] + red[2][2] + red[3][2];
    float tnc = red[0][3] + red[1][3] + red[2][3] + red[3][3];
    float sp = tps / fmaxf(tpc, 1.f);
    float sn = tns / fmaxf(tnc, 1.f);
    out[33554432] = fmaxf(sn - sp + 1.f, 0.f);
  }
}

// ---------------------------------------------------------------------------
extern "C" void kernel_launch(void* const* d_in, const int* in_sizes, int n_in,
                              void* d_out, int out_size, void* d_ws, size_t ws_size,
                              hipStream_t stream) {
  const float* x  = (const float*)d_in[0];
  const float* W  = (const float*)d_in[1];
  const float* b  = (const float*)d_in[2];
  const float* rp = (const float*)d_in[3];
  const int*  ids = (const int*)d_in[4];
  float* out = (float*)d_out;
  char* ws = (char*)d_ws;

  unsigned short* swb = (unsigned short*)(ws);                 // 64 MiB
  unsigned short* xb  = (unsigned short*)(ws + 67108864);      //  2 MiB
  float*          sbg = (float*)(ws + 69206016);               // 128 KiB
  unsigned short* qnb = (unsigned short*)(ws + 69337088);      // 256 KiB
  unsigned short* wnb = (unsigned short*)(ws + 69599232);      //  8 MiB
  float*         scal = (float*)(ws + 78012416);               // 8 floats
  float4*        part = (float4*)(ws + 78016512);              // 32 KiB

  k_gather   <<<2304,  256, 0, stream>>>(W, b, x, ids, swb, sbg, xb, scal, rp, qnb);
  k_wn       <<<256,   256, 0, stream>>>(swb, rp, sbg, wnb);
  k_gemm_main<<<2048,  256, 0, stream>>>(xb, swb, sbg, out);
  k_hist     <<<1024, 1024, 0, stream>>>(out, sbg, scal);
  k_sim      <<<2048,  256, 0, stream>>>(qnb, wnb, out, sbg, scal, part);
  k_final    <<<1,     256, 0, stream>>>(part, out);
}

// Round 17
// 278.675 us; speedup vs baseline: 1.5512x; 1.0987x over previous
//
#include <hip/hip_runtime.h>

// ---------------------------------------------------------------------------
// LSHSampledLayer: logits = x @ W[ids]^T + b[ids]; kth-value thresholds;
// masked-mean cosine-sim triplet loss on random projections.
// N=1024, D=K=1024, C=S=32768, P=128.
// ---------------------------------------------------------------------------

using short8v = __attribute__((ext_vector_type(8))) short;
using f32x4   = __attribute__((ext_vector_type(4))) float;

#define AS1C(p) ((const __attribute__((address_space(1))) void*)(p))
#define AS3(p)  ((__attribute__((address_space(3))) void*)(p))

__device__ __forceinline__ unsigned short f2bf(float f) {
  union { float f; unsigned u; } v; v.f = f;
  unsigned u = v.u;
  return (unsigned short)((u + 0x7FFFu + ((u >> 16) & 1u)) >> 16);  // RNE
}
__device__ __forceinline__ float bf2f(unsigned short s) {
  return __uint_as_float(((unsigned)s) << 16);
}

// ---- K1: pure gather: W[ids]->bf16, b[ids]->f32, cast x->bf16 --------------
__global__ __launch_bounds__(256) void k_gather(
    const float* __restrict__ W, const float* __restrict__ bb,
    const float* __restrict__ x, const int* __restrict__ ids,
    unsigned short* __restrict__ swb, float* __restrict__ sbg,
    unsigned short* __restrict__ xb, float* __restrict__ scal) {
  const int t = threadIdx.x;
  if (blockIdx.x == 0 && t < 8) scal[t] = 0.f;  // zero accumulators
  for (int blk = blockIdx.x; blk < 33792; blk += 2048) {
    if (blk < 32768) {
      const int id = ids[blk];
      float4 v = *(const float4*)&W[(size_t)id * 1024 + t * 4];
      ushort4 o; o.x = f2bf(v.x); o.y = f2bf(v.y); o.z = f2bf(v.z); o.w = f2bf(v.w);
      *(ushort4*)&swb[(size_t)blk * 1024 + t * 4] = o;
      if (t == 0) sbg[blk] = bb[id];
    } else {
      const int r = blk - 32768;
      float4 v = *(const float4*)&x[(size_t)r * 1024 + t * 4];
      ushort4 o; o.x = f2bf(v.x); o.y = f2bf(v.y); o.z = f2bf(v.z); o.w = f2bf(v.w);
      *(ushort4*)&xb[(size_t)r * 1024 + t * 4] = o;
    }
  }
}

// ---- swizzled staging: 128x32 bf16 tile, global -> LDS ---------------------
// Row-major linear dest (coalesced); within-row chunk XOR c' = c ^ ((row>>1)&3)
// applied on the SOURCE; reads use the same involution -> 2-way = free.
__device__ __forceinline__ void stage_sw(const unsigned short* g, int lda,
                                         unsigned short* l, int t) {
#pragma unroll
  for (int i = 0; i < 2; ++i) {
    const int idx = i * 256 + t;
    const int row = idx >> 2;
    const int c = (idx & 3) ^ ((row >> 1) & 3);
    const unsigned short* gp = g + (size_t)row * lda + c * 8;
    __builtin_amdgcn_global_load_lds(AS1C(gp), AS3(l + idx * 8), 16, 0, 0);
  }
}

__device__ __forceinline__ void stage_rp(const float* __restrict__ rp, int k0,
                                         unsigned short* l, int t) {
#pragma unroll
  for (int ii = 0; ii < 4; ++ii) {
    int idx = ii * 256 + t;            // 0..1023
    int kk = idx & 31, c4 = idx >> 5;  // kk fast -> conflict-free LDS writes
    float4 v = *(const float4*)&rp[(size_t)(k0 + kk) * 128 + c4 * 4];
    l[(c4 * 4 + 0) * 32 + kk] = f2bf(v.x);
    l[(c4 * 4 + 1) * 32 + kk] = f2bf(v.y);
    l[(c4 * 4 + 2) * 32 + kk] = f2bf(v.z);
    l[(c4 * 4 + 3) * 32 + kk] = f2bf(v.w);
  }
}

// ---- K3: k_proj -- blocks 0..255: wn = normalize([W[ids],b]@rp) -> wnb -----
//          blocks 256..263: qn = normalize([x,1]@rp) -> qnb (bias = 1.0)
// Replaces the scalar-rp qn path (1024 serial scalar loads/thread) with the
// same MFMA pipeline used for wn -- identical math, same layout.
__global__ __launch_bounds__(256) void k_proj(
    const unsigned short* __restrict__ swb, const unsigned short* __restrict__ xb,
    const float* __restrict__ rp, const float* __restrict__ sbg,
    unsigned short* __restrict__ wnb, unsigned short* __restrict__ qnb) {
  __shared__ unsigned short As[2][128 * 32];
  __shared__ unsigned short Bs[2][128 * 32];
  __shared__ float nbuf[2][128];
  const int t = threadIdx.x;
  const bool isq = blockIdx.x >= 256;
  const int r0 = (isq ? (blockIdx.x - 256) : blockIdx.x) * 128;
  const unsigned short* Ag = (isq ? xb : swb) + (size_t)r0 * 1024;
  unsigned short* outp = isq ? qnb : wnb;
  f32x4 acc[4][4];
#pragma unroll
  for (int m = 0; m < 4; ++m)
#pragma unroll
    for (int n = 0; n < 4; ++n) acc[m][n] = f32x4{0.f, 0.f, 0.f, 0.f};
  stage_sw(Ag, 1024, &As[0][0], t);
  stage_rp(rp, 0, &Bs[0][0], t);
  const int l = t & 63, w = t >> 6, wm = w >> 1, wn = w & 1;
  const int lr = l & 15, lk = l >> 4;
  const int kch = lk * 8;
  const int ach = (lk ^ ((lr >> 1) & 3)) * 8;  // swizzled chunk for A reads
  for (int kt = 0; kt < 32; ++kt) {
    const int cur = kt & 1;
    __syncthreads();
    if (kt + 1 < 32) {
      stage_sw(Ag + (kt + 1) * 32, 1024, &As[cur ^ 1][0], t);
      stage_rp(rp, (kt + 1) * 32, &Bs[cur ^ 1][0], t);
    }
    short8v a[4], b[4];
#pragma unroll
    for (int m = 0; m < 4; ++m) a[m] = *(const short8v*)&As[cur][(wm * 64 + m * 16 + lr) * 32 + ach];
#pragma unroll
    for (int n = 0; n < 4; ++n) b[n] = *(const short8v*)&Bs[cur][(wn * 64 + n * 16 + lr) * 32 + kch];
#pragma unroll
    for (int m = 0; m < 4; ++m)
#pragma unroll
      for (int n = 0; n < 4; ++n)
        acc[m][n] = __builtin_amdgcn_mfma_f32_16x16x32_bf16(a[m], b[n], acc[m][n], 0, 0, 0);
  }
  const float* rpl = rp + (size_t)1024 * 128;
  float sb_r[4][4];
#pragma unroll
  for (int m = 0; m < 4; ++m)
#pragma unroll
    for (int i = 0; i < 4; ++i)
      sb_r[m][i] = isq ? 1.f : sbg[r0 + wm * 64 + m * 16 + lk * 4 + i];
#pragma unroll
  for (int n = 0; n < 4; ++n) {
    const int gc = wn * 64 + n * 16 + lr;
    const float rl = rpl[gc];
#pragma unroll
    for (int m = 0; m < 4; ++m)
#pragma unroll
      for (int i = 0; i < 4; ++i) acc[m][n][i] += sb_r[m][i] * rl;
  }
#pragma unroll
  for (int m = 0; m < 4; ++m)
#pragma unroll
    for (int i = 0; i < 4; ++i) {
      float s = 0.f;
#pragma unroll
      for (int n = 0; n < 4; ++n) s += acc[m][n][i] * acc[m][n][i];
#pragma unroll
      for (int msk = 1; msk < 16; msk <<= 1) s += __shfl_xor(s, msk, 64);
      if (lr == 0) nbuf[wn][wm * 64 + m * 16 + lk * 4 + i] = s;
    }
  __syncthreads();
#pragma unroll
  for (int m = 0; m < 4; ++m)
#pragma unroll
    for (int i = 0; i < 4; ++i) {
      const int lrow = wm * 64 + m * 16 + lk * 4 + i;
      const float n2 = nbuf[0][lrow] + nbuf[1][lrow];
      const float sc = 1.f / fmaxf(sqrtf(n2), 1e-6f);
#pragma unroll
      for (int n = 0; n < 4; ++n) {
        const int gc = wn * 64 + n * 16 + lr;
        outp[(size_t)(r0 + lrow) * 128 + gc] = f2bf(acc[m][n][i] * sc);
      }
    }
}

// ---- K4: main GEMM  logits = xb @ swb^T + sb  (128x128, R9-proven) ---------
__global__ __launch_bounds__(256) void k_gemm_main(
    const unsigned short* __restrict__ A, const unsigned short* __restrict__ B,
    const float* __restrict__ sbg, float* __restrict__ out) {
  __shared__ unsigned short As[2][128 * 32];
  __shared__ unsigned short Bs[2][128 * 32];
  const int t = threadIdx.x;
  // 2048 blocks, 8 XCDs, 256 logical tiles per XCD (nwg%8==0 -> bijective)
  const int lb = (blockIdx.x & 7) * 256 + (blockIdx.x >> 3);
  const int bm = lb & 7, bn = lb >> 3;
  const unsigned short* Ag = A + (size_t)bm * 128 * 1024;
  const unsigned short* Bg = B + (size_t)bn * 128 * 1024;
  f32x4 acc[2][8];
#pragma unroll
  for (int m = 0; m < 2; ++m)
#pragma unroll
    for (int n = 0; n < 8; ++n) acc[m][n] = f32x4{0.f, 0.f, 0.f, 0.f};
  stage_sw(Ag, 1024, &As[0][0], t);
  stage_sw(Bg, 1024, &Bs[0][0], t);
  const int l = t & 63, w = t >> 6;        // wave w owns rows w*32..w*32+31
  const int lr = l & 15, lk = l >> 4;
  const int ach = (lk ^ ((lr >> 1) & 3)) * 8;  // swizzled chunk (per-lane const)
  for (int kt = 0; kt < 32; ++kt) {
    const int cur = kt & 1;
    __syncthreads();
    if (kt + 1 < 32) {
      stage_sw(Ag + (kt + 1) * 32, 1024, &As[cur ^ 1][0], t);
      stage_sw(Bg + (kt + 1) * 32, 1024, &Bs[cur ^ 1][0], t);
    }
    short8v a[2], b[8];
#pragma unroll
    for (int m = 0; m < 2; ++m)
      a[m] = *(const short8v*)&As[cur][(w * 32 + m * 16 + lr) * 32 + ach];
#pragma unroll
    for (int n = 0; n < 8; ++n)
      b[n] = *(const short8v*)&Bs[cur][(n * 16 + lr) * 32 + ach];
#pragma unroll
    for (int m = 0; m < 2; ++m)
#pragma unroll
      for (int n = 0; n < 8; ++n)
        acc[m][n] = __builtin_amdgcn_mfma_f32_16x16x32_bf16(a[m], b[n], acc[m][n], 0, 0, 0);
  }
  const int rb = bm * 128 + w * 32, cb = bn * 128;
#pragma unroll
  for (int n = 0; n < 8; ++n) {
    const int gc = cb + n * 16 + lr;
    const float bias = sbg[gc];
#pragma unroll
    for (int m = 0; m < 2; ++m)
#pragma unroll
      for (int i = 0; i < 4; ++i) {
        const int gr = rb + m * 16 + lk * 4 + i;
        out[(size_t)gr * 32768 + gc] = acc[m][n][i] + bias;
      }
  }
}

// ---- K5: single-HBM-pass bf16-exact kthvalue (1024 thr -> 32 waves/CU) -----
__global__ __launch_bounds__(1024) void k_hist(
    const float* __restrict__ logits, const float* __restrict__ sbg,
    float* __restrict__ scal) {
  __shared__ unsigned short rowm[32768];  // 64 KiB mapped keys
  __shared__ unsigned hist[2048];
  __shared__ unsigned scanbuf[1024];
  __shared__ unsigned hsub[64];
  __shared__ int res[4];
  const int t = threadIdx.x, row = blockIdx.x;
  for (int i = t; i < 2048; i += 1024) hist[i] = 0u;
  if (t < 64) hsub[t] = 0u;
  __syncthreads();
  const float* lp = logits + (size_t)row * 32768;
  for (int c = t * 4; c < 32768; c += 4096) {
    const float4 lv = *(const float4*)&lp[c];
    const float4 sb4 = *(const float4*)&sbg[c];
    const float pr[4] = {lv.x - sb4.x, lv.y - sb4.y, lv.z - sb4.z, lv.w - sb4.w};
    unsigned short mm[4];
#pragma unroll
    for (int j = 0; j < 4; ++j) {
      const unsigned short bbf = f2bf(pr[j]);
      const unsigned m = (bbf & 0x8000u) ? (0xFFFFu ^ (unsigned)bbf)
                                         : ((unsigned)bbf | 0x8000u);
      mm[j] = (unsigned short)m;
      atomicAdd(&hist[m >> 5], 1u);
    }
    *(ushort4*)&rowm[c] = make_ushort4(mm[0], mm[1], mm[2], mm[3]);
  }
  __syncthreads();
  {  // 2048-bin scan over 1024 threads (2 bins each)
    unsigned s = hist[t * 2] + hist[t * 2 + 1];
    scanbuf[t] = s;
    __syncthreads();
    unsigned x = s;
    for (int off = 1; off < 1024; off <<= 1) {
      unsigned y = (t >= off) ? scanbuf[t - off] : 0u;
      __syncthreads();
      x += y; scanbuf[t] = x;
      __syncthreads();
    }
    unsigned run = x - s;
    const unsigned K1R = 32734u, K2R = 16383u;  // 0-indexed kth ranks
#pragma unroll
    for (int j = 0; j < 2; ++j) {
      unsigned c = hist[t * 2 + j];
      if (K1R >= run && K1R < run + c) { res[0] = t * 2 + j; res[1] = (int)(K1R - run); }
      if (K2R >= run && K2R < run + c) { res[2] = t * 2 + j; res[3] = (int)(K2R - run); }
      run += c;
    }
  }
  __syncthreads();
  const unsigned bin1 = (unsigned)res[0], r1 = (unsigned)res[1];
  const unsigned bin2 = (unsigned)res[2], r2 = (unsigned)res[3];
  for (int c = t; c < 32768; c += 1024) {
    const unsigned m = rowm[c];
    const unsigned bq = m >> 5;
    if (bq == bin1) atomicAdd(&hsub[m & 31], 1u);
    if (bq == bin2) atomicAdd(&hsub[32 + (m & 31)], 1u);
  }
  __syncthreads();
  if (t == 0) {
    unsigned a_ = 0; int sub1 = 31;
    for (int j = 0; j < 32; ++j) { if (r1 < a_ + hsub[j]) { sub1 = j; break; } a_ += hsub[j]; }
    a_ = 0; int sub2 = 31;
    for (int j = 0; j < 32; ++j) { if (r2 < a_ + hsub[32 + j]) { sub2 = j; break; } a_ += hsub[32 + j]; }
    const unsigned m1 = (bin1 << 5) | (unsigned)sub1;
    const unsigned m2 = (bin2 << 5) | (unsigned)sub2;
    const float kv1 = bf2f((unsigned short)((m1 & 0x8000u) ? (m1 & 0x7FFFu) : (0xFFFFu ^ m1)));
    const float kv2 = bf2f((unsigned short)((m2 & 0x8000u) ? (m2 & 0x7FFFu) : (0xFFFFu ^ m2)));
    atomicAdd(&scal[0], kv1);   // kth-value sums; k_sim divides by 1024
    atomicAdd(&scal[1], kv2);
  }
}

// ---- K7: sim = qn @ wn^T fused with masked sums ----------------------------
// A fragments global->reg (qnb L2-resident); B tile staged ONCE (one drain +
// one barrier); 64 MFMA; simb unions over the B LDS.
__global__ __launch_bounds__(256) void k_sim(
    const unsigned short* __restrict__ A, const unsigned short* __restrict__ B,
    const float* __restrict__ logits, const float* __restrict__ sbg,
    const float* __restrict__ scal, float4* __restrict__ part) {
  __shared__ unsigned short smem[128 * 128];  // 32 KiB: Bs4[4][128*32] -> simb -> red
  unsigned short* simb = smem;
  float* red = (float*)smem;
  const int t = threadIdx.x;
  const int bm = blockIdx.x & 7, bn = blockIdx.x >> 3;
  const unsigned short* Ag = A + (size_t)bm * 128 * 128;
  const unsigned short* Bg = B + (size_t)bn * 128 * 128;
  const int l = t & 63, w = t >> 6, wm = w >> 1, wn = w & 1;
  const int lr = l & 15, lk = l >> 4;
  const int ach = (lk ^ ((lr >> 1) & 3)) * 8;
#pragma unroll
  for (int kt = 0; kt < 4; ++kt)
    stage_sw(Bg + kt * 32, 128, &smem[kt * 4096], t);
  short8v af[4][4];
#pragma unroll
  for (int m = 0; m < 4; ++m)
#pragma unroll
    for (int kt = 0; kt < 4; ++kt)
      af[m][kt] = *(const short8v*)&Ag[(size_t)(wm * 64 + m * 16 + lr) * 128 + kt * 32 + lk * 8];
  f32x4 acc[4][4];
#pragma unroll
  for (int m = 0; m < 4; ++m)
#pragma unroll
    for (int n = 0; n < 4; ++n) acc[m][n] = f32x4{0.f, 0.f, 0.f, 0.f};
  __syncthreads();  // B tile landed
#pragma unroll
  for (int kt = 0; kt < 4; ++kt) {
    short8v b[4];
#pragma unroll
    for (int n = 0; n < 4; ++n)
      b[n] = *(const short8v*)&smem[kt * 4096 + (wn * 64 + n * 16 + lr) * 32 + ach];
#pragma unroll
    for (int m = 0; m < 4; ++m)
#pragma unroll
      for (int n = 0; n < 4; ++n)
        acc[m][n] = __builtin_amdgcn_mfma_f32_16x16x32_bf16(af[m][kt], b[n], acc[m][n], 0, 0, 0);
  }
  __syncthreads();  // all B reads done before simb overwrites smem
#pragma unroll
  for (int m = 0; m < 4; ++m)
#pragma unroll
    for (int n = 0; n < 4; ++n) {
      const int col = wn * 64 + n * 16 + lr;
#pragma unroll
      for (int i = 0; i < 4; ++i) {
        const int row = wm * 64 + m * 16 + lk * 4 + i;
        simb[row * 128 + col] = f2bf(acc[m][n][i]);
      }
    }
  __syncthreads();
  const float t1 = fmaxf(scal[0] * (1.f / 1024.f), 0.f);
  const float t2 = scal[1] * (1.f / 1024.f);
  const int rb0 = bm * 128, cb0 = bn * 128;
  const int c4 = t & 31, rbase = t >> 5;
  const float4 sb4 = *(const float4*)&sbg[cb0 + c4 * 4];
  float ps = 0.f, pc = 0.f, ns = 0.f, nc = 0.f;
#pragma unroll
  for (int it = 0; it < 16; ++it) {
    const int rr = it * 8 + rbase;
    const float4 lv = *(const float4*)&logits[(size_t)(rb0 + rr) * 32768 + cb0 + c4 * 4];
    const ushort4 sv = *(const ushort4*)&simb[rr * 128 + c4 * 4];
    const float pr[4] = {lv.x - sb4.x, lv.y - sb4.y, lv.z - sb4.z, lv.w - sb4.w};
    const float sm[4] = {bf2f(sv.x), bf2f(sv.y), bf2f(sv.z), bf2f(sv.w)};
#pragma unroll
    for (int j = 0; j < 4; ++j) {
      if (pr[j] > t1) { ps += sm[j]; pc += 1.f; }
      if (pr[j] < t2) { ns += sm[j]; nc += 1.f; }
    }
  }
#pragma unroll
  for (int m = 1; m < 64; m <<= 1) {
    ps += __shfl_xor(ps, m, 64); pc += __shfl_xor(pc, m, 64);
    ns += __shfl_xor(ns, m, 64); nc += __shfl_xor(nc, m, 64);
  }
  __syncthreads();  // all simb reads done before red aliases it
  if (l == 0) { red[w * 4 + 0] = ps; red[w * 4 + 1] = pc; red[w * 4 + 2] = ns; red[w * 4 + 3] = nc; }
  __syncthreads();
  if (t == 0) {
    float4 o;
    o.x = red[0] + red[4] + red[8]  + red[12];
    o.y = red[1] + red[5] + red[9]  + red[13];
    o.z = red[2] + red[6] + red[10] + red[14];
    o.w = red[3] + red[7] + red[11] + red[15];
    part[blockIdx.x] = o;
  }
}

// ---- K8: reduce per-block partials, finalize triplet loss ------------------
__global__ __launch_bounds__(256) void k_final(
    const float4* __restrict__ part, float* __restrict__ out) {
  __shared__ float red[4][4];
  const int t = threadIdx.x;
  float ps = 0.f, pc = 0.f, ns = 0.f, nc = 0.f;
  for (int i = t; i < 2048; i += 256) {
    float4 v = part[i];
    ps += v.x; pc += v.y; ns += v.z; nc += v.w;
  }
#pragma unroll
  for (int m = 1; m < 64; m <<= 1) {
    ps += __shfl_xor(ps, m, 64); pc += __shfl_xor(pc, m, 64);
    ns += __shfl_xor(ns, m, 64); nc += __shfl_xor(nc, m, 64);
  }
  const int w = t >> 6;
  if ((t & 63) == 0) { red[w][0] = ps; red[w][1] = pc; red[w][2] = ns; red[w][3] = nc; }
  __syncthreads();
  if (t == 0) {
    float tps = red[0][0] + red[1][0] + red[2][0] + red[3][0];
    float tpc = red[0][1] + red[1][1] + red[2][1] + red[3][1];
    float tns = red[0][2] + red[1][2] + red[2][2] + red[3][2];
    float tnc = red[0][3] + red[1][3] + red[2][3] + red[3][3];
    float sp = tps / fmaxf(tpc, 1.f);
    float sn = tns / fmaxf(tnc, 1.f);
    out[33554432] = fmaxf(sn - sp + 1.f, 0.f);
  }
}

// ---------------------------------------------------------------------------
extern "C" void kernel_launch(void* const* d_in, const int* in_sizes, int n_in,
                              void* d_out, int out_size, void* d_ws, size_t ws_size,
                              hipStream_t stream) {
  const float* x  = (const float*)d_in[0];
  const float* W  = (const float*)d_in[1];
  const float* b  = (const float*)d_in[2];
  const float* rp = (const float*)d_in[3];
  const int*  ids = (const int*)d_in[4];
  float* out = (float*)d_out;
  char* ws = (char*)d_ws;

  unsigned short* swb = (unsigned short*)(ws);                 // 64 MiB
  unsigned short* xb  = (unsigned short*)(ws + 67108864);      //  2 MiB
  float*          sbg = (float*)(ws + 69206016);               // 128 KiB
  unsigned short* qnb = (unsigned short*)(ws + 69337088);      // 256 KiB
  unsigned short* wnb = (unsigned short*)(ws + 69599232);      //  8 MiB
  float*         scal = (float*)(ws + 78012416);               // 8 floats
  float4*        part = (float4*)(ws + 78016512);              // 32 KiB

  k_gather   <<<2048,  256, 0, stream>>>(W, b, x, ids, swb, sbg, xb, scal);
  k_proj     <<<264,   256, 0, stream>>>(swb, xb, rp, sbg, wnb, qnb);
  k_gemm_main<<<2048,  256, 0, stream>>>(xb, swb, sbg, out);
  k_hist     <<<1024, 1024, 0, stream>>>(out, sbg, scal);
  k_sim      <<<2048,  256, 0, stream>>>(qnb, wnb, out, sbg, scal, part);
  k_final    <<<1,     256, 0, stream>>>(part, out);
}